// Round 19
// baseline (216.123 us; speedup 1.0000x reference)
//
#include <hip/hip_runtime.h>
#include <hip/hip_bf16.h>
#include <math.h>

// Problem constants
#define Hh 192
#define Ww 192
#define HWp (Hh*Ww)          // 36864
#define Bb 2
#define Cch 64
#define DI 128
#define NWX 24               // windows per row
#define WPB 576              // windows per batch
#define NW  1152             // total windows
#define DS 16
#define SHIFT 4

typedef __attribute__((ext_vector_type(8))) short short8v;  // 8 bf16 (4 VGPRs)
typedef __attribute__((ext_vector_type(4))) float f32x4;    // MFMA accumulator

// ------------------- K0: pre-pack weight LDS-images (once per launch) -------------------
__global__ __launch_bounds__(256) void k_prep(
    const float* __restrict__ in_w, const float* __restrict__ out_w,
    const float* __restrict__ w1, const float* __restrict__ w2, const float* __restrict__ xp,
    __hip_bfloat16* __restrict__ inT, __hip_bfloat16* __restrict__ outT,
    __hip_bfloat16* __restrict__ w1i, __hip_bfloat16* __restrict__ w2i,
    float* __restrict__ xpi){
  int i = blockIdx.x*256 + threadIdx.x;
  if (i < 18432) {
    int o = i/72, c = i%72;
    inT[i] = (__hip_bfloat16)((c < 64) ? in_w[c*256 + o] : 0.f);
    return;
  }
  i -= 18432;
  if (i < 8704) {
    int o = i/136, c = i%136;
    outT[i] = (__hip_bfloat16)((c < 128) ? out_w[c*64 + o] : 0.f);
    return;
  }
  i -= 8704;
  if (i < 10368) {
    int tap = i/1152, r = i%1152, co = r/72, ci = r%72;
    w1i[i] = (__hip_bfloat16)((ci < 64) ? w1[(co*64 + ci)*9 + tap] : 0.f);
    return;
  }
  i -= 10368;
  if (i < 12800) {
    int p = i/2560, r = i%2560, co = r/40, k = r%40;
    float v = 0.f;
    if (k < 32) { int tap = p*2 + (k>>4); int ci = k & 15; if (tap < 9) v = w2[co*144 + ci*9 + tap]; }
    w2i[i] = (__hip_bfloat16)v;
    return;
  }
  i -= 12800;
  if (i < 4736) {
    int c = i/37, j = i%37;
    xpi[i] = (j < 36) ? xp[c*36 + j] : 0.f;
  }
}

// ------------------- K1: NCHW -> NHWC transpose -------------------
__global__ __launch_bounds__(256) void k_transpose(const float* __restrict__ x, float* __restrict__ xT){
  __shared__ float t[64][65];
  int b   = blockIdx.x / WPB;
  int hw0 = (blockIdx.x % WPB) * 64;
  int lane = threadIdx.x & 63, grp = threadIdx.x >> 6;
  const float* xb = x + (size_t)b * Cch * HWp;
  #pragma unroll
  for (int r = 0; r < 64; r += 4) {
    int c = r + grp;
    t[c][lane] = xb[(size_t)c * HWp + hw0 + lane];
  }
  __syncthreads();
  float* xo = xT + ((size_t)b * HWp + hw0) * 64;
  #pragma unroll
  for (int r = 0; r < 64; r += 4) {
    int hwl = r + grp;
    xo[(size_t)hwl * 64 + lane] = t[lane][hwl];
  }
}

// ------------------- K2: shift + LN1 + in_proj(MFMA) + mask + conv1d(split) + silu + dbc ---------
// LDS time-multiplex: buf holds in_w image (MFMA phase) then XZ[64][133] (conv/dbc phases).
__global__ __launch_bounds__(256) void k_stage1(
    const float* __restrict__ xT, const float* __restrict__ g1, const float* __restrict__ b1,
    const __hip_bfloat16* __restrict__ inT, const float* __restrict__ in_b,
    const float* __restrict__ conv_w, const float* __restrict__ conv_b,
    const float* __restrict__ xpi,
    float* __restrict__ xc, float* __restrict__ Zb, float* __restrict__ dbc){
  __shared__ __align__(16) __hip_bfloat16 xs[64][72];   // 9.2 KB
  __shared__ __align__(16) float buf[9216];             // 36.9 KB: wt bf16 [256][72] -> XZ f32 [64][133]
  __hip_bfloat16* wt = reinterpret_cast<__hip_bfloat16*>(buf);
  float (*XZ)[133] = reinterpret_cast<float(*)[133]>(buf);
  int n = blockIdx.x;
  int b = n / WPB, wi = n % WPB;
  int wy = wi / NWX, wx = wi % NWX;
  int tid = threadIdx.x;
  // phase 0: stage in_w^T image + LN1
  {
    short8v* dst = reinterpret_cast<short8v*>(wt);
    const short8v* src = reinterpret_cast<const short8v*>(inT);
    for (int idx = tid; idx < 2304; idx += 256) dst[idx] = src[idx];
  }
  {
    int l = tid >> 2, q = tid & 3;
    int iy = l >> 3, ix = l & 7;
    int h = wy*8 + iy, w = wx*8 + ix;
    int hs = h + SHIFT; if (hs >= Hh) hs -= Hh;
    int ws2 = w + SHIFT; if (ws2 >= Ww) ws2 -= Ww;
    const float* src = xT + ((size_t)b*HWp + (size_t)hs*Ww + ws2) * 64 + q*16;
    float v[16];
    float s1 = 0.f, s2 = 0.f;
    #pragma unroll
    for (int k = 0; k < 4; k++) {
      float4 f = *reinterpret_cast<const float4*>(src + k*4);
      v[k*4+0]=f.x; v[k*4+1]=f.y; v[k*4+2]=f.z; v[k*4+3]=f.w;
    }
    #pragma unroll
    for (int i = 0; i < 16; i++) { s1 += v[i]; s2 += v[i]*v[i]; }
    s1 += __shfl_xor(s1, 1); s2 += __shfl_xor(s2, 1);
    s1 += __shfl_xor(s1, 2); s2 += __shfl_xor(s2, 2);
    float mu = s1 * (1.f/64.f);
    float var = s2 * (1.f/64.f) - mu*mu;
    float rstd = rsqrtf(var + 1e-5f);
    __hip_bfloat16 tmp[16];
    #pragma unroll
    for (int i = 0; i < 16; i++) {
      int c = q*16 + i;
      tmp[i] = (__hip_bfloat16)((v[i]-mu)*rstd*g1[c] + b1[c]);
    }
    *reinterpret_cast<short8v*>(&xs[l][q*16])     = *reinterpret_cast<short8v*>(&tmp[0]);
    *reinterpret_cast<short8v*>(&xs[l][q*16 + 8]) = *reinterpret_cast<short8v*>(&tmp[8]);
  }
  __syncthreads();
  // phase 1: MFMA (reads xs + wt)
  int w_ = tid >> 6, lane = tid & 63;
  int col = lane & 15, g = lane >> 4;
  f32x4 acc[4][4];
  {
    short8v af[4][2];
    #pragma unroll
    for (int m = 0; m < 4; m++)
      #pragma unroll
      for (int kh = 0; kh < 2; kh++)
        af[m][kh] = *reinterpret_cast<const short8v*>(&xs[m*16 + col][kh*32 + g*8]);
    #pragma unroll
    for (int m = 0; m < 4; m++)
      #pragma unroll
      for (int nt = 0; nt < 4; nt++)
        acc[m][nt] = (f32x4){0.f,0.f,0.f,0.f};
    #pragma unroll
    for (int nt = 0; nt < 4; nt++) {
      int o = (w_*4 + nt)*16 + col;
      #pragma unroll
      for (int kh = 0; kh < 2; kh++) {
        short8v bf = *reinterpret_cast<const short8v*>(&wt[o*72 + kh*32 + g*8]);
        #pragma unroll
        for (int m = 0; m < 4; m++)
          acc[m][nt] = __builtin_amdgcn_mfma_f32_16x16x32_bf16(af[m][kh], bf, acc[m][nt], 0, 0, 0);
      }
    }
  }
  __syncthreads();   // all wt reads done; buf may be overwritten as XZ
  // phase 2: C-write (XZ aliased over buf; Zb to global)
  {
    #pragma unroll
    for (int nt = 0; nt < 4; nt++) {
      int colg = (w_*4 + nt)*16 + col;
      float bias = in_b[colg];
      #pragma unroll
      for (int m = 0; m < 4; m++) {
        #pragma unroll
        for (int j = 0; j < 4; j++) {
          int row = m*16 + g*4 + j;
          float val = acc[m][nt][j] + bias;
          if (colg < 128) XZ[row][colg] = val;
          else Zb[((size_t)n*64 + row)*128 + (colg - 128)] = val;
        }
      }
    }
  }
  __syncthreads();
  // phase 3: conv1d FIR split (tokens 0-31 | 32-63), halo from XZ
  {
    int d = tid & 127, half = tid >> 7;
    int t0 = half * 32;
    float cw0 = conv_w[d], cw1 = conv_w[128+d], cw2 = conv_w[256+d], cw3 = conv_w[384+d];
    float cb = conv_b[d];
    float p1 = 0.f, p2 = 0.f, p3 = 0.f;
    if (half) {
      int hh, ww2;
      hh = wy*8 + (31>>3); ww2 = wx*8 + (31&7);
      p1 = XZ[31][d] * ((hh < Hh-SHIFT && ww2 < Ww-SHIFT) ? 1.f : 0.f);
      hh = wy*8 + (30>>3); ww2 = wx*8 + (30&7);
      p2 = XZ[30][d] * ((hh < Hh-SHIFT && ww2 < Ww-SHIFT) ? 1.f : 0.f);
      hh = wy*8 + (29>>3); ww2 = wx*8 + (29&7);
      p3 = XZ[29][d] * ((hh < Hh-SHIFT && ww2 < Ww-SHIFT) ? 1.f : 0.f);
    }
    __syncthreads();   // halo reads complete before overwrite
    float* Xn = xc + (size_t)n*8192;
    #pragma unroll 4
    for (int i = 0; i < 32; i++) {
      int t = t0 + i;
      int hh = wy*8 + (t>>3), ww2 = wx*8 + (t&7);
      float m = (hh < Hh-SHIFT && ww2 < Ww-SHIFT) ? 1.f : 0.f;
      float xv = XZ[t][d] * m;
      float pre = cw3*xv + cw2*p1 + cw1*p2 + cw0*p3 + cb;
      float sv = pre / (1.f + __expf(-pre));
      Xn[t*128 + d] = sv;
      XZ[t][d] = sv;
      p3 = p2; p2 = p1; p1 = xv;
    }
  }
  __syncthreads();
  // phase 4: dbc GEMM. t = tid&63, jq = tid>>6 (wave-uniform -> scalar xpi loads from L2)
  {
    int t = tid & 63, jq = tid >> 6;
    const float* wrow = xpi + jq*9;
    float acc2[9];
    #pragma unroll
    for (int u = 0; u < 9; u++) acc2[u] = 0.f;
    for (int c = 0; c < 128; c++) {
      float xv = XZ[t][c];
      const float* wr = wrow + c*37;
      #pragma unroll
      for (int u = 0; u < 9; u++) acc2[u] += xv * wr[u];
    }
    float* dst = dbc + ((size_t)n*64 + t)*36 + jq*9;
    #pragma unroll
    for (int u = 0; u < 9; u++) dst[u] = acc2[u];
  }
}

// ------------------- K4: dt + scan + gate; db rows via wave-uniform scalar loads -----------------
__global__ __launch_bounds__(128) void k_scan3(
    float* __restrict__ xc,           // in: xc ; out: g = (y + D*xc)*silu(z)
    const float* __restrict__ Zb, const float* __restrict__ dbc,
    const float* __restrict__ dt_w, const float* __restrict__ dt_b,
    const float* __restrict__ A_log, const float* __restrict__ Dp){
  int n = blockIdx.x;
  int d = threadIdx.x;  // 0..127
  const float* Dn = dbc + (size_t)n*2304;   // uniform base
  float dtb  = dt_b[d];
  float dtw0 = dt_w[d], dtw1 = dt_w[128+d], dtw2 = dt_w[256+d], dtw3 = dt_w[384+d];
  float Dd = Dp[d];
  float a[16];
  bool pow_ok = true;
  #pragma unroll
  for (int s = 0; s < 16; s++) {
    a[s] = -__expf(A_log[d*16+s]);
    pow_ok = pow_ok && (__builtin_fabsf(a[s] + (float)(s+1)) < 1e-3f);
  }
  float h[16];
  #pragma unroll
  for (int s = 0; s < 16; s++) h[s] = 0.f;
  const float* Xn = xc + (size_t)n*8192;
  const float* Zn = Zb + (size_t)n*8192;
  float* Gn = xc + (size_t)n*8192;
  if (pow_ok) {
    #pragma unroll 2
    for (int i = 0; i < 64; i++) {
      const float* row = Dn + i*36;   // uniform across wave -> scalar loads
      float4 dv = *reinterpret_cast<const float4*>(row);
      float4 B0 = *reinterpret_cast<const float4*>(row + 4);
      float4 B1 = *reinterpret_cast<const float4*>(row + 8);
      float4 B2 = *reinterpret_cast<const float4*>(row + 12);
      float4 B3 = *reinterpret_cast<const float4*>(row + 16);
      float4 C0 = *reinterpret_cast<const float4*>(row + 20);
      float4 C1 = *reinterpret_cast<const float4*>(row + 24);
      float4 C2 = *reinterpret_cast<const float4*>(row + 28);
      float4 C3 = *reinterpret_cast<const float4*>(row + 32);
      float pre = dtb + dv.x*dtw0 + dv.y*dtw1 + dv.z*dtw2 + dv.w*dtw3;
      float dtv = (pre > 15.f) ? pre : __logf(1.f + __expf(pre));
      float xcv = Xn[i*128 + d];
      float zv  = Zn[i*128 + d];
      float du  = dtv * xcv;
      float P[16];
      P[0] = __expf(-dtv);
      #pragma unroll
      for (int s = 1; s < 16; s++) {
        int aa = (s-1) >> 1, bb = (s-1) - aa;
        P[s] = P[aa] * P[bb];
      }
      h[0]  = P[0]*h[0]  + du*B0.x;  h[1]  = P[1]*h[1]  + du*B0.y;
      h[2]  = P[2]*h[2]  + du*B0.z;  h[3]  = P[3]*h[3]  + du*B0.w;
      h[4]  = P[4]*h[4]  + du*B1.x;  h[5]  = P[5]*h[5]  + du*B1.y;
      h[6]  = P[6]*h[6]  + du*B1.z;  h[7]  = P[7]*h[7]  + du*B1.w;
      h[8]  = P[8]*h[8]  + du*B2.x;  h[9]  = P[9]*h[9]  + du*B2.y;
      h[10] = P[10]*h[10]+ du*B2.z;  h[11] = P[11]*h[11]+ du*B2.w;
      h[12] = P[12]*h[12]+ du*B3.x;  h[13] = P[13]*h[13]+ du*B3.y;
      h[14] = P[14]*h[14]+ du*B3.z;  h[15] = P[15]*h[15]+ du*B3.w;
      float y0 = h[0]*C0.x + h[1]*C0.y;   y0 += h[2]*C0.z + h[3]*C0.w;
      float y1 = h[4]*C1.x + h[5]*C1.y;   y1 += h[6]*C1.z + h[7]*C1.w;
      float y2 = h[8]*C2.x + h[9]*C2.y;   y2 += h[10]*C2.z + h[11]*C2.w;
      float y3 = h[12]*C3.x + h[13]*C3.y; y3 += h[14]*C3.z + h[15]*C3.w;
      float y = (y0 + y1) + (y2 + y3);
      float yv = y + Dd*xcv;
      Gn[i*128 + d] = yv * (zv / (1.f + __expf(-zv)));
    }
  } else {
    #pragma unroll 2
    for (int i = 0; i < 64; i++) {
      const float* row = Dn + i*36;
      float4 dv = *reinterpret_cast<const float4*>(row);
      float pre = dtb + dv.x*dtw0 + dv.y*dtw1 + dv.z*dtw2 + dv.w*dtw3;
      float dtv = (pre > 15.f) ? pre : __logf(1.f + __expf(pre));
      float xcv = Xn[i*128 + d];
      float zv  = Zn[i*128 + d];
      float du  = dtv * xcv;
      float y = 0.f;
      #pragma unroll
      for (int s = 0; s < 16; s++) {
        float e = __expf(dtv * a[s]);
        h[s] = e*h[s] + du*row[4+s];
        y += h[s]*row[20+s];
      }
      float yv = y + Dd*xcv;
      Gn[i*128 + d] = yv * (zv / (1.f + __expf(-zv)));
    }
  }
}

// ------------------- K5: out_proj (bf16 MFMA) + window-reverse + skip1 + LN2 -------------------
// LDS time-multiplex: buf2 holds out_w image (MFMA phase) then outs[64][65] (epilogue).
__global__ __launch_bounds__(256) void k_out(
    const float* __restrict__ xT, const float* __restrict__ g,
    const __hip_bfloat16* __restrict__ outT, const float* __restrict__ out_b,
    const float* __restrict__ skip1, const float* __restrict__ g2, const float* __restrict__ b2,
    float* __restrict__ x1, float* __restrict__ x2){
  __shared__ __align__(16) __hip_bfloat16 gs[64][136];  // 17.4 KB
  __shared__ __align__(16) float buf2[4352];            // 17.4 KB: wt bf16 [64][136] -> outs f32 [64][65]
  __hip_bfloat16* wt = reinterpret_cast<__hip_bfloat16*>(buf2);
  float (*outs)[65] = reinterpret_cast<float(*)[65]>(buf2);
  int n = blockIdx.x;
  int b = n / WPB, wi = n % WPB;
  int wy = wi / NWX, wx = wi % NWX;
  int tid = threadIdx.x;
  const float4* src = reinterpret_cast<const float4*>(g + (size_t)n*8192);
  #pragma unroll
  for (int k = 0; k < 8; k++) {
    int gi = tid + k*256;
    int t = gi >> 5, d4 = gi & 31;
    float4 v = src[gi];
    __hip_bfloat16 tmp[4] = {(__hip_bfloat16)v.x,(__hip_bfloat16)v.y,(__hip_bfloat16)v.z,(__hip_bfloat16)v.w};
    *reinterpret_cast<ushort4*>(&gs[t][d4*4]) = *reinterpret_cast<ushort4*>(tmp);
  }
  {
    short8v* dst = reinterpret_cast<short8v*>(wt);
    const short8v* wsrc = reinterpret_cast<const short8v*>(outT);
    for (int idx = tid; idx < 1088; idx += 256) dst[idx] = wsrc[idx];
  }
  __syncthreads();
  int w = tid >> 6, lane = tid & 63;
  int col = lane & 15, gq = lane >> 4;
  f32x4 acc[4] = {{0.f,0.f,0.f,0.f},{0.f,0.f,0.f,0.f},{0.f,0.f,0.f,0.f},{0.f,0.f,0.f,0.f}};
  {
    #pragma unroll
    for (int kh = 0; kh < 4; kh++) {
      short8v af = *reinterpret_cast<const short8v*>(&gs[w*16 + col][kh*32 + gq*8]);
      #pragma unroll
      for (int nt = 0; nt < 4; nt++) {
        short8v bf = *reinterpret_cast<const short8v*>(&wt[(nt*16 + col)*136 + kh*32 + gq*8]);
        acc[nt] = __builtin_amdgcn_mfma_f32_16x16x32_bf16(af, bf, acc[nt], 0, 0, 0);
      }
    }
  }
  __syncthreads();   // wt reads done; buf2 may be overwritten as outs
  {
    #pragma unroll
    for (int nt = 0; nt < 4; nt++) {
      int o = nt*16 + col;
      float bias = out_b[o];
      #pragma unroll
      for (int j = 0; j < 4; j++)
        outs[w*16 + gq*4 + j][o] = acc[nt][j] + bias;
    }
  }
  __syncthreads();
  int l = tid >> 2, q = tid & 3;
  int hh = wy*8 + (l>>3), ww2 = wx*8 + (l&7);
  size_t T = (size_t)b*HWp + (size_t)hh*Ww + ww2;
  float v[16];
  float s1 = 0.f, s2 = 0.f;
  #pragma unroll
  for (int i = 0; i < 16; i++) {
    int c = q*16 + i;
    float val = xT[T*64 + c] * skip1[c] + outs[l][c];
    v[i] = val; s1 += val; s2 += val*val;
  }
  s1 += __shfl_xor(s1, 1); s2 += __shfl_xor(s2, 1);
  s1 += __shfl_xor(s1, 2); s2 += __shfl_xor(s2, 2);
  float mu = s1*(1.f/64.f);
  float var = s2*(1.f/64.f) - mu*mu;
  float rstd = rsqrtf(var + 1e-5f);
  #pragma unroll
  for (int i = 0; i < 16; i++) {
    int c = q*16 + i;
    x1[T*64 + c] = v[i];
    x2[T*64 + c] = (v[i]-mu)*rstd*g2[c] + b2[c];
  }
}

// ------------------- K6: CAB conv1 3x3 64->16 + gelu (bf16 MFMA implicit GEMM) -------------------
__global__ __launch_bounds__(256) void k_conv1(
    const float* __restrict__ x2, const __hip_bfloat16* __restrict__ w1i, const float* __restrict__ bc1,
    __hip_bfloat16* __restrict__ c1){
  __shared__ __align__(16) __hip_bfloat16 xt[100][72];   // 14.4 KB
  __shared__ __align__(16) __hip_bfloat16 wt[9][16][72]; // 20.7 KB [tap][co][ci] image
  int b = blockIdx.x / WPB;
  int r = blockIdx.x % WPB;
  int by = r / NWX, bx = r % NWX;
  {
    short8v* dst = reinterpret_cast<short8v*>(&wt[0][0][0]);
    const short8v* src = reinterpret_cast<const short8v*>(w1i);
    for (int idx = threadIdx.x; idx < 1296; idx += 256) dst[idx] = src[idx];
  }
  for (int idx = threadIdx.x; idx < 1600; idx += 256) {
    int p = idx >> 4, c4 = idx & 15;
    int gy = by*8 + p/10 - 1;
    int gx = bx*8 + p%10 - 1;
    float4 v = make_float4(0.f,0.f,0.f,0.f);
    if (gy >= 0 && gy < Hh && gx >= 0 && gx < Ww)
      v = *reinterpret_cast<const float4*>(&x2[((size_t)b*HWp + (size_t)gy*Ww + gx)*64 + c4*4]);
    __hip_bfloat16 tmp[4] = {(__hip_bfloat16)v.x,(__hip_bfloat16)v.y,(__hip_bfloat16)v.z,(__hip_bfloat16)v.w};
    *reinterpret_cast<ushort4*>(&xt[p][c4*4]) = *reinterpret_cast<ushort4*>(tmp);
  }
  __syncthreads();
  int wv = threadIdx.x >> 6;
  int l  = threadIdx.x & 63;
  int col = l & 15, g = l >> 4;
  int apix = wv*16 + col;
  int apy = apix >> 3, apx = apix & 7;
  f32x4 acc = {0.f,0.f,0.f,0.f};
  #pragma unroll
  for (int tap = 0; tap < 9; tap++) {
    int ky = tap/3, kx = tap%3;
    const __hip_bfloat16* arow = &xt[(apy+ky)*10 + apx+kx][0];
    #pragma unroll
    for (int kh = 0; kh < 2; kh++) {
      short8v af = *reinterpret_cast<const short8v*>(&arow[kh*32 + g*8]);
      short8v bf = *reinterpret_cast<const short8v*>(&wt[tap][col][kh*32 + g*8]);
      acc = __builtin_amdgcn_mfma_f32_16x16x32_bf16(af, bf, acc, 0, 0, 0);
    }
  }
  float bias = bc1[col];
  #pragma unroll
  for (int j = 0; j < 4; j++) {
    int opix = wv*16 + g*4 + j;
    int oy = by*8 + (opix>>3), ox = bx*8 + (opix&7);
    float v = acc[j] + bias;
    float gv = 0.5f * v * (1.f + erff(v * 0.70710678118f));
    c1[((size_t)b*HWp + (size_t)oy*Ww + ox)*16 + col] = (__hip_bfloat16)gv;
  }
}

// ------------------- K7: CAB conv2 3x3 16->64 + partial mean (bf16 MFMA implicit GEMM) ------------
__global__ __launch_bounds__(256) void k_conv2(
    const __hip_bfloat16* __restrict__ c1, const __hip_bfloat16* __restrict__ w2i, const float* __restrict__ bc2,
    float* __restrict__ c2, float* __restrict__ sums){
  __shared__ __align__(16) __hip_bfloat16 xt[100][16];   // 3.2 KB
  __shared__ __align__(16) __hip_bfloat16 wt[5][64][40]; // 25.6 KB [pair][co][k] image
  __shared__ float red[4][64];
  int b = blockIdx.x / WPB;
  int r = blockIdx.x % WPB;
  int by = r / NWX, bx = r % NWX;
  {
    short8v* dst = reinterpret_cast<short8v*>(&wt[0][0][0]);
    const short8v* src = reinterpret_cast<const short8v*>(w2i);
    for (int idx = threadIdx.x; idx < 1600; idx += 256) dst[idx] = src[idx];
  }
  for (int idx = threadIdx.x; idx < 400; idx += 256) {
    int p = idx >> 2, c4 = idx & 3;
    int gy = by*8 + p/10 - 1;
    int gx = bx*8 + p%10 - 1;
    ushort4 v = {0,0,0,0};
    if (gy >= 0 && gy < Hh && gx >= 0 && gx < Ww)
      v = *reinterpret_cast<const ushort4*>(&c1[((size_t)b*HWp + (size_t)gy*Ww + gx)*16 + c4*4]);
    *reinterpret_cast<ushort4*>(&xt[p][c4*4]) = v;
  }
  __syncthreads();
  int wv4 = threadIdx.x >> 6;
  int l   = threadIdx.x & 63;
  int col = l & 15, g = l >> 4;
  int apix = wv4*16 + col;
  int apy = apix >> 3, apx = apix & 7;
  f32x4 acc[4] = {{0.f,0.f,0.f,0.f},{0.f,0.f,0.f,0.f},{0.f,0.f,0.f,0.f},{0.f,0.f,0.f,0.f}};
  #pragma unroll
  for (int p = 0; p < 5; p++) {
    int tap = p*2 + (g >> 1); if (tap > 8) tap = 8;
    int ky = tap/3, kx = tap%3;
    short8v af = *reinterpret_cast<const short8v*>(&xt[(apy+ky)*10 + apx+kx][(g&1)*8]);
    #pragma unroll
    for (int ct = 0; ct < 4; ct++) {
      short8v bf = *reinterpret_cast<const short8v*>(&wt[p][ct*16 + col][g*8]);
      acc[ct] = __builtin_amdgcn_mfma_f32_16x16x32_bf16(af, bf, acc[ct], 0, 0, 0);
    }
  }
  #pragma unroll
  for (int ct = 0; ct < 4; ct++) {
    int co = ct*16 + col;
    float bias = bc2[co];
    float part = 0.f;
    #pragma unroll
    for (int j = 0; j < 4; j++) {
      int opix = wv4*16 + g*4 + j;
      int oy = by*8 + (opix>>3), ox = bx*8 + (opix&7);
      float v = acc[ct][j] + bias;
      c2[((size_t)b*HWp + (size_t)oy*Ww + ox)*64 + co] = v;
      part += v;
    }
    part += __shfl_xor(part, 16);
    part += __shfl_xor(part, 32);
    if (g == 0) red[wv4][co] = part;
  }
  __syncthreads();
  if (threadIdx.x < 64) {
    float s = red[0][threadIdx.x] + red[1][threadIdx.x] + red[2][threadIdx.x] + red[3][threadIdx.x];
    atomicAdd(&sums[b*64 + threadIdx.x], s);
  }
}

// ------------------- K8: channel attention -------------------
__global__ void k_att(const float* __restrict__ sums,
                      const float* __restrict__ wd, const float* __restrict__ bd,
                      const float* __restrict__ wu, const float* __restrict__ bu,
                      float* __restrict__ att){
  int tid = threadIdx.x;            // 128 threads
  int b = tid >> 6, co = tid & 63;
  float inv = 1.f / (float)HWp;
  float hid[4];
  #pragma unroll
  for (int j = 0; j < 4; j++) {
    float acc = bd[j];
    for (int c = 0; c < 64; c++) acc += wd[j*64+c] * (sums[b*64+c] * inv);
    hid[j] = fmaxf(acc, 0.f);
  }
  float acc = bu[co];
  #pragma unroll
  for (int j = 0; j < 4; j++) acc += wu[co*4+j] * hid[j];
  att[tid] = 1.f / (1.f + __expf(-acc));
}

// ------------------- K9: final combine + NHWC -> NCHW -------------------
__global__ __launch_bounds__(256) void k_final(
    const float* __restrict__ x1, const float* __restrict__ c2,
    const float* __restrict__ skip2, const float* __restrict__ att,
    float* __restrict__ out){
  __shared__ float t[64][65];
  int b = blockIdx.x / WPB;
  int hw0 = (blockIdx.x % WPB) * 64;
  int lane = threadIdx.x & 63, grp = threadIdx.x >> 6;
  float sk = skip2[lane], at = att[b*64 + lane];
  #pragma unroll
  for (int r = 0; r < 64; r += 4) {
    int hwl = r + grp;
    size_t T = (size_t)b*HWp + hw0 + hwl;
    t[hwl][lane] = x1[T*64+lane]*sk + c2[T*64+lane]*at;
  }
  __syncthreads();
  float* ob = out + (size_t)b * Cch * HWp;
  #pragma unroll
  for (int r = 0; r < 64; r += 4) {
    int c = r + grp;
    ob[(size_t)c*HWp + hw0 + lane] = t[lane][c];
  }
}

extern "C" void kernel_launch(void* const* d_in, const int* in_sizes, int n_in,
                              void* d_out, int out_size, void* d_ws, size_t ws_size,
                              hipStream_t stream) {
  (void)in_sizes; (void)n_in; (void)out_size; (void)ws_size;
  const float* x      = (const float*)d_in[0];
  const float* ln1_g  = (const float*)d_in[1];
  const float* ln1_b  = (const float*)d_in[2];
  const float* in_w   = (const float*)d_in[3];
  const float* in_b   = (const float*)d_in[4];
  const float* conv_w = (const float*)d_in[5];
  const float* conv_b = (const float*)d_in[6];
  const float* xproj_w= (const float*)d_in[7];
  const float* dt_w   = (const float*)d_in[8];
  const float* dt_b   = (const float*)d_in[9];
  const float* A_log  = (const float*)d_in[10];
  const float* Dp     = (const float*)d_in[11];
  const float* out_w  = (const float*)d_in[12];
  const float* out_b  = (const float*)d_in[13];
  const float* skip1  = (const float*)d_in[14];
  const float* ln2_g  = (const float*)d_in[15];
  const float* ln2_b  = (const float*)d_in[16];
  const float* skip2  = (const float*)d_in[17];
  const float* cab_w1 = (const float*)d_in[18];
  const float* cab_b1 = (const float*)d_in[19];
  const float* cab_w2 = (const float*)d_in[20];
  const float* cab_b2 = (const float*)d_in[21];
  const float* ca_wd  = (const float*)d_in[22];
  const float* ca_bd  = (const float*)d_in[23];
  const float* ca_wu  = (const float*)d_in[24];
  const float* ca_bu  = (const float*)d_in[25];

  float* ws   = (float*)d_ws;
  float* xT   = ws;                        // [0, 4718592)
  float* xc   = ws + 4718592;              // g in-place; c2 aliases later
  float* z    = ws + 14155776;             // x1/x2 alias later
  float* dbc  = ws + 23592960;             // c1 aliases later
  float* sums = ws + 26247168;             // 128
  float* att  = ws + 26247296;             // 128
  float* x1   = ws + 14155776;             // alias over z
  float* x2   = ws + 18874368;             // alias over z second half
  __hip_bfloat16* c1 = (__hip_bfloat16*)(ws + 23592960); // alias over dbc
  float* c2   = ws + 4718592;              // alias over xc/g
  // prep area (weight images)
  __hip_bfloat16* inT  = (__hip_bfloat16*)(ws + 26247424); // 18432 bf16
  __hip_bfloat16* outT = (__hip_bfloat16*)(ws + 26256640); // 8704 bf16
  __hip_bfloat16* w1i  = (__hip_bfloat16*)(ws + 26260992); // 10368 bf16
  __hip_bfloat16* w2i  = (__hip_bfloat16*)(ws + 26266176); // 12800 bf16
  float*          xpi  = ws + 26272576;                    // 4736 f

  hipMemsetAsync(sums, 0, 128*sizeof(float), stream);
  k_prep<<<215, 256, 0, stream>>>(in_w, out_w, cab_w1, cab_w2, xproj_w,
                                  inT, outT, w1i, w2i, xpi);
  k_transpose<<<NW, 256, 0, stream>>>(x, xT);
  k_stage1<<<NW, 256, 0, stream>>>(xT, ln1_g, ln1_b, inT, in_b, conv_w, conv_b, xpi,
                                   xc, z, dbc);
  k_scan3<<<NW, 128, 0, stream>>>(xc, z, dbc, dt_w, dt_b, A_log, Dp);
  k_out<<<NW, 256, 0, stream>>>(xT, xc, outT, out_b, skip1, ln2_g, ln2_b, x1, x2);
  k_conv1<<<NW, 256, 0, stream>>>(x2, w1i, cab_b1, c1);
  k_conv2<<<NW, 256, 0, stream>>>(c1, w2i, cab_b2, c2, sums);
  k_att<<<1, 128, 0, stream>>>(sums, ca_wd, ca_bd, ca_wu, ca_bu, att);
  k_final<<<NW, 256, 0, stream>>>(x1, c2, skip2, att, (float*)d_out);
}

// Round 20
// 203.259 us; speedup vs baseline: 1.0633x; 1.0633x over previous
//
#include <hip/hip_runtime.h>
#include <hip/hip_bf16.h>
#include <math.h>

// Problem constants
#define Hh 192
#define Ww 192
#define HWp (Hh*Ww)          // 36864
#define Bb 2
#define Cch 64
#define DI 128
#define NWX 24               // windows per row
#define WPB 576              // windows per batch
#define NW  1152             // total windows
#define DS 16
#define SHIFT 4

typedef __attribute__((ext_vector_type(8))) short short8v;  // 8 bf16 (4 VGPRs)
typedef __attribute__((ext_vector_type(4))) float f32x4;    // MFMA accumulator

// ------------------- K0: pre-pack weight LDS-images (once per launch) -------------------
__global__ __launch_bounds__(256) void k_prep(
    const float* __restrict__ in_w, const float* __restrict__ out_w,
    const float* __restrict__ w1, const float* __restrict__ w2, const float* __restrict__ xp,
    __hip_bfloat16* __restrict__ inT, __hip_bfloat16* __restrict__ outT,
    __hip_bfloat16* __restrict__ w1i, __hip_bfloat16* __restrict__ w2i,
    float* __restrict__ xpi){
  int i = blockIdx.x*256 + threadIdx.x;
  if (i < 18432) {
    int o = i/72, c = i%72;
    inT[i] = (__hip_bfloat16)((c < 64) ? in_w[c*256 + o] : 0.f);
    return;
  }
  i -= 18432;
  if (i < 8704) {
    int o = i/136, c = i%136;
    outT[i] = (__hip_bfloat16)((c < 128) ? out_w[c*64 + o] : 0.f);
    return;
  }
  i -= 8704;
  if (i < 10368) {
    int tap = i/1152, r = i%1152, co = r/72, ci = r%72;
    w1i[i] = (__hip_bfloat16)((ci < 64) ? w1[(co*64 + ci)*9 + tap] : 0.f);
    return;
  }
  i -= 10368;
  if (i < 12800) {
    int p = i/2560, r = i%2560, co = r/40, k = r%40;
    float v = 0.f;
    if (k < 32) { int tap = p*2 + (k>>4); int ci = k & 15; if (tap < 9) v = w2[co*144 + ci*9 + tap]; }
    w2i[i] = (__hip_bfloat16)v;
    return;
  }
  i -= 12800;
  if (i < 4736) {
    int c = i/37, j = i%37;
    xpi[i] = (j < 36) ? xp[c*36 + j] : 0.f;
  }
}

// ------------------- K1: NCHW -> NHWC transpose -------------------
__global__ __launch_bounds__(256) void k_transpose(const float* __restrict__ x, float* __restrict__ xT){
  __shared__ float t[64][65];
  int b   = blockIdx.x / WPB;
  int hw0 = (blockIdx.x % WPB) * 64;
  int lane = threadIdx.x & 63, grp = threadIdx.x >> 6;
  const float* xb = x + (size_t)b * Cch * HWp;
  #pragma unroll
  for (int r = 0; r < 64; r += 4) {
    int c = r + grp;
    t[c][lane] = xb[(size_t)c * HWp + hw0 + lane];
  }
  __syncthreads();
  float* xo = xT + ((size_t)b * HWp + hw0) * 64;
  #pragma unroll
  for (int r = 0; r < 64; r += 4) {
    int hwl = r + grp;
    xo[(size_t)hwl * 64 + lane] = t[lane][hwl];
  }
}

// ------------------- K2: shift + LN1 + in_proj(MFMA) + mask + conv1d(split) + silu + dbc ---------
__global__ __launch_bounds__(256) void k_stage1(
    const float* __restrict__ xT, const float* __restrict__ g1, const float* __restrict__ b1,
    const __hip_bfloat16* __restrict__ inT, const float* __restrict__ in_b,
    const float* __restrict__ conv_w, const float* __restrict__ conv_b,
    const float* __restrict__ xpi,
    __hip_bfloat16* __restrict__ xc, __hip_bfloat16* __restrict__ Zb, float* __restrict__ dbc){
  __shared__ __align__(16) __hip_bfloat16 xs[64][72];   // 9.2 KB
  __shared__ __align__(16) __hip_bfloat16 wt[256][72];  // 36.9 KB; reused later as wsx[128][37] f32
  __shared__ __align__(16) float XZ[64][132];           // 33.8 KB (x_in half -> xc after conv)
  float* wsx = reinterpret_cast<float*>(&wt[0][0]);
  int n = blockIdx.x;
  int b = n / WPB, wi = n % WPB;
  int wy = wi / NWX, wx = wi % NWX;
  int tid = threadIdx.x;
  // stage pre-packed in_w^T image (contiguous, conflict-free)
  {
    short8v* dst = reinterpret_cast<short8v*>(&wt[0][0]);
    const short8v* src = reinterpret_cast<const short8v*>(inT);
    for (int idx = tid; idx < 2304; idx += 256) dst[idx] = src[idx];
  }
  {
    int l = tid >> 2, q = tid & 3;
    int iy = l >> 3, ix = l & 7;
    int h = wy*8 + iy, w = wx*8 + ix;
    int hs = h + SHIFT; if (hs >= Hh) hs -= Hh;
    int ws2 = w + SHIFT; if (ws2 >= Ww) ws2 -= Ww;
    const float* src = xT + ((size_t)b*HWp + (size_t)hs*Ww + ws2) * 64 + q*16;
    float v[16];
    float s1 = 0.f, s2 = 0.f;
    #pragma unroll
    for (int k = 0; k < 4; k++) {
      float4 f = *reinterpret_cast<const float4*>(src + k*4);
      v[k*4+0]=f.x; v[k*4+1]=f.y; v[k*4+2]=f.z; v[k*4+3]=f.w;
    }
    #pragma unroll
    for (int i = 0; i < 16; i++) { s1 += v[i]; s2 += v[i]*v[i]; }
    s1 += __shfl_xor(s1, 1); s2 += __shfl_xor(s2, 1);
    s1 += __shfl_xor(s1, 2); s2 += __shfl_xor(s2, 2);
    float mu = s1 * (1.f/64.f);
    float var = s2 * (1.f/64.f) - mu*mu;
    float rstd = rsqrtf(var + 1e-5f);
    __hip_bfloat16 tmp[16];
    #pragma unroll
    for (int i = 0; i < 16; i++) {
      int c = q*16 + i;
      tmp[i] = (__hip_bfloat16)((v[i]-mu)*rstd*g1[c] + b1[c]);
    }
    *reinterpret_cast<short8v*>(&xs[l][q*16])     = *reinterpret_cast<short8v*>(&tmp[0]);
    *reinterpret_cast<short8v*>(&xs[l][q*16 + 8]) = *reinterpret_cast<short8v*>(&tmp[8]);
  }
  __syncthreads();
  {
    int w = tid >> 6, lane = tid & 63;
    int col = lane & 15, g = lane >> 4;
    short8v af[4][2];
    #pragma unroll
    for (int m = 0; m < 4; m++)
      #pragma unroll
      for (int kh = 0; kh < 2; kh++)
        af[m][kh] = *reinterpret_cast<const short8v*>(&xs[m*16 + col][kh*32 + g*8]);
    f32x4 acc[4][4];
    #pragma unroll
    for (int m = 0; m < 4; m++)
      #pragma unroll
      for (int nt = 0; nt < 4; nt++)
        acc[m][nt] = (f32x4){0.f,0.f,0.f,0.f};
    #pragma unroll
    for (int nt = 0; nt < 4; nt++) {
      int o = (w*4 + nt)*16 + col;
      #pragma unroll
      for (int kh = 0; kh < 2; kh++) {
        short8v bf = *reinterpret_cast<const short8v*>(&wt[o][kh*32 + g*8]);
        #pragma unroll
        for (int m = 0; m < 4; m++)
          acc[m][nt] = __builtin_amdgcn_mfma_f32_16x16x32_bf16(af[m][kh], bf, acc[m][nt], 0, 0, 0);
      }
    }
    #pragma unroll
    for (int nt = 0; nt < 4; nt++) {
      int colg = (w*4 + nt)*16 + col;
      float bias = in_b[colg];
      #pragma unroll
      for (int m = 0; m < 4; m++) {
        #pragma unroll
        for (int j = 0; j < 4; j++) {
          int row = m*16 + g*4 + j;
          float val = acc[m][nt][j] + bias;
          if (colg < 128) XZ[row][colg] = val;
          else Zb[((size_t)n*64 + row)*128 + (colg - 128)] = (__hip_bfloat16)val;
        }
      }
    }
  }
  __syncthreads();
  // conv epilogue: FIR split across 2 thread-halves (tokens 0-31 | 32-63), halo from XZ
  {
    int d = tid & 127, half = tid >> 7;
    int t0 = half * 32;
    float cw0 = conv_w[d], cw1 = conv_w[128+d], cw2 = conv_w[256+d], cw3 = conv_w[384+d];
    float cb = conv_b[d];
    float p1 = 0.f, p2 = 0.f, p3 = 0.f;
    if (half) {
      int hh, ww2;
      hh = wy*8 + (31>>3); ww2 = wx*8 + (31&7);
      p1 = XZ[31][d] * ((hh < Hh-SHIFT && ww2 < Ww-SHIFT) ? 1.f : 0.f);
      hh = wy*8 + (30>>3); ww2 = wx*8 + (30&7);
      p2 = XZ[30][d] * ((hh < Hh-SHIFT && ww2 < Ww-SHIFT) ? 1.f : 0.f);
      hh = wy*8 + (29>>3); ww2 = wx*8 + (29&7);
      p3 = XZ[29][d] * ((hh < Hh-SHIFT && ww2 < Ww-SHIFT) ? 1.f : 0.f);
    }
    __syncthreads();   // halo reads complete before any overwrite
    __hip_bfloat16* Xn = xc + (size_t)n*8192;
    #pragma unroll 4
    for (int i = 0; i < 32; i++) {
      int t = t0 + i;
      int hh = wy*8 + (t>>3), ww2 = wx*8 + (t&7);
      float m = (hh < Hh-SHIFT && ww2 < Ww-SHIFT) ? 1.f : 0.f;
      float xv = XZ[t][d] * m;
      float pre = cw3*xv + cw2*p1 + cw1*p2 + cw0*p3 + cb;
      float sv = pre / (1.f + __expf(-pre));
      Xn[t*128 + d] = (__hip_bfloat16)sv;
      XZ[t][d] = sv;
      p3 = p2; p2 = p1; p1 = xv;
    }
  }
  __syncthreads();
  // copy xproj image into dead wt buffer (fp32 [128][37])
  {
    float4* dst = reinterpret_cast<float4*>(wsx);
    const float4* src = reinterpret_cast<const float4*>(xpi);
    for (int idx = tid; idx < 1184; idx += 256) dst[idx] = src[idx];
  }
  __syncthreads();
  // dbc GEMM: 64 tokens x 36 outs, 4 threads/token x 9 outs
  {
    int t = tid >> 2, jq = tid & 3;
    float acc[9];
    #pragma unroll
    for (int u = 0; u < 9; u++) acc[u] = 0.f;
    for (int c = 0; c < 128; c++) {
      float xv = XZ[t][c];
      #pragma unroll
      for (int u = 0; u < 9; u++) acc[u] += xv * wsx[c*37 + jq*9+u];
    }
    float* dst = dbc + ((size_t)n*64 + t)*36 + jq*9;
    #pragma unroll
    for (int u = 0; u < 9; u++) dst[u] = acc[u];
  }
}

// ------------------- K4: dt + scan + gate; db rows via wave-uniform scalar loads -----------------
__global__ __launch_bounds__(128) void k_scan3(
    __hip_bfloat16* __restrict__ xc,  // in: xc ; out: g = (y + D*xc)*silu(z)  (bf16)
    const __hip_bfloat16* __restrict__ Zb, const float* __restrict__ dbc,
    const float* __restrict__ dt_w, const float* __restrict__ dt_b,
    const float* __restrict__ A_log, const float* __restrict__ Dp){
  int n = blockIdx.x;
  int d = threadIdx.x;  // 0..127
  const float* Dn = dbc + (size_t)n*2304;   // uniform base
  float dtb  = dt_b[d];
  float dtw0 = dt_w[d], dtw1 = dt_w[128+d], dtw2 = dt_w[256+d], dtw3 = dt_w[384+d];
  float Dd = Dp[d];
  float a[16];
  bool pow_ok = true;
  #pragma unroll
  for (int s = 0; s < 16; s++) {
    a[s] = -__expf(A_log[d*16+s]);
    pow_ok = pow_ok && (__builtin_fabsf(a[s] + (float)(s+1)) < 1e-3f);
  }
  float h[16];
  #pragma unroll
  for (int s = 0; s < 16; s++) h[s] = 0.f;
  const __hip_bfloat16* Xn = xc + (size_t)n*8192;
  const __hip_bfloat16* Zn = Zb + (size_t)n*8192;
  __hip_bfloat16* Gn = xc + (size_t)n*8192;
  if (pow_ok) {
    #pragma unroll 2
    for (int i = 0; i < 64; i++) {
      const float* row = Dn + i*36;   // uniform across wave -> scalar loads
      float4 dv = *reinterpret_cast<const float4*>(row);
      float4 B0 = *reinterpret_cast<const float4*>(row + 4);
      float4 B1 = *reinterpret_cast<const float4*>(row + 8);
      float4 B2 = *reinterpret_cast<const float4*>(row + 12);
      float4 B3 = *reinterpret_cast<const float4*>(row + 16);
      float4 C0 = *reinterpret_cast<const float4*>(row + 20);
      float4 C1 = *reinterpret_cast<const float4*>(row + 24);
      float4 C2 = *reinterpret_cast<const float4*>(row + 28);
      float4 C3 = *reinterpret_cast<const float4*>(row + 32);
      float pre = dtb + dv.x*dtw0 + dv.y*dtw1 + dv.z*dtw2 + dv.w*dtw3;
      float dtv = (pre > 15.f) ? pre : __logf(1.f + __expf(pre));
      float xcv = __bfloat162float(Xn[i*128 + d]);
      float zv  = __bfloat162float(Zn[i*128 + d]);
      float du  = dtv * xcv;
      float P[16];
      P[0] = __expf(-dtv);
      #pragma unroll
      for (int s = 1; s < 16; s++) {
        int aa = (s-1) >> 1, bb = (s-1) - aa;
        P[s] = P[aa] * P[bb];
      }
      h[0]  = P[0]*h[0]  + du*B0.x;  h[1]  = P[1]*h[1]  + du*B0.y;
      h[2]  = P[2]*h[2]  + du*B0.z;  h[3]  = P[3]*h[3]  + du*B0.w;
      h[4]  = P[4]*h[4]  + du*B1.x;  h[5]  = P[5]*h[5]  + du*B1.y;
      h[6]  = P[6]*h[6]  + du*B1.z;  h[7]  = P[7]*h[7]  + du*B1.w;
      h[8]  = P[8]*h[8]  + du*B2.x;  h[9]  = P[9]*h[9]  + du*B2.y;
      h[10] = P[10]*h[10]+ du*B2.z;  h[11] = P[11]*h[11]+ du*B2.w;
      h[12] = P[12]*h[12]+ du*B3.x;  h[13] = P[13]*h[13]+ du*B3.y;
      h[14] = P[14]*h[14]+ du*B3.z;  h[15] = P[15]*h[15]+ du*B3.w;
      float y0 = h[0]*C0.x + h[1]*C0.y;   y0 += h[2]*C0.z + h[3]*C0.w;
      float y1 = h[4]*C1.x + h[5]*C1.y;   y1 += h[6]*C1.z + h[7]*C1.w;
      float y2 = h[8]*C2.x + h[9]*C2.y;   y2 += h[10]*C2.z + h[11]*C2.w;
      float y3 = h[12]*C3.x + h[13]*C3.y; y3 += h[14]*C3.z + h[15]*C3.w;
      float y = (y0 + y1) + (y2 + y3);
      float yv = y + Dd*xcv;
      Gn[i*128 + d] = (__hip_bfloat16)(yv * (zv / (1.f + __expf(-zv))));
    }
  } else {
    #pragma unroll 2
    for (int i = 0; i < 64; i++) {
      const float* row = Dn + i*36;
      float4 dv = *reinterpret_cast<const float4*>(row);
      float pre = dtb + dv.x*dtw0 + dv.y*dtw1 + dv.z*dtw2 + dv.w*dtw3;
      float dtv = (pre > 15.f) ? pre : __logf(1.f + __expf(pre));
      float xcv = __bfloat162float(Xn[i*128 + d]);
      float zv  = __bfloat162float(Zn[i*128 + d]);
      float du  = dtv * xcv;
      float y = 0.f;
      #pragma unroll
      for (int s = 0; s < 16; s++) {
        float e = __expf(dtv * a[s]);
        h[s] = e*h[s] + du*row[4+s];
        y += h[s]*row[20+s];
      }
      float yv = y + Dd*xcv;
      Gn[i*128 + d] = (__hip_bfloat16)(yv * (zv / (1.f + __expf(-zv))));
    }
  }
}

// ------------------- K5: out_proj (bf16 MFMA) + window-reverse + skip1 + LN2 -------------------
__global__ __launch_bounds__(256) void k_out(
    const float* __restrict__ xT, const __hip_bfloat16* __restrict__ g,
    const __hip_bfloat16* __restrict__ outT, const float* __restrict__ out_b,
    const float* __restrict__ skip1, const float* __restrict__ g2, const float* __restrict__ b2,
    float* __restrict__ x1, float* __restrict__ x2){
  __shared__ __align__(16) __hip_bfloat16 gs[64][136];  // 17.4 KB
  __shared__ __align__(16) __hip_bfloat16 wt[64][136];  // 17.4 KB (out_w^T image)
  __shared__ float outs[64][65];                        // 16.6 KB
  int n = blockIdx.x;
  int b = n / WPB, wi = n % WPB;
  int wy = wi / NWX, wx = wi % NWX;
  int tid = threadIdx.x;
  // stage g (bf16 memcpy into padded rows)
  {
    const short8v* src = reinterpret_cast<const short8v*>(g + (size_t)n*8192);
    for (int idx = tid; idx < 1024; idx += 256) {
      int t = idx >> 4, seg = idx & 15;
      *reinterpret_cast<short8v*>(&gs[t][seg*8]) = src[idx];
    }
  }
  {
    short8v* dst = reinterpret_cast<short8v*>(&wt[0][0]);
    const short8v* wsrc = reinterpret_cast<const short8v*>(outT);
    for (int idx = tid; idx < 1088; idx += 256) dst[idx] = wsrc[idx];
  }
  __syncthreads();
  {
    int w = tid >> 6, lane = tid & 63;
    int col = lane & 15, gq = lane >> 4;
    f32x4 acc[4] = {{0.f,0.f,0.f,0.f},{0.f,0.f,0.f,0.f},{0.f,0.f,0.f,0.f},{0.f,0.f,0.f,0.f}};
    #pragma unroll
    for (int kh = 0; kh < 4; kh++) {
      short8v af = *reinterpret_cast<const short8v*>(&gs[w*16 + col][kh*32 + gq*8]);
      #pragma unroll
      for (int nt = 0; nt < 4; nt++) {
        short8v bf = *reinterpret_cast<const short8v*>(&wt[nt*16 + col][kh*32 + gq*8]);
        acc[nt] = __builtin_amdgcn_mfma_f32_16x16x32_bf16(af, bf, acc[nt], 0, 0, 0);
      }
    }
    #pragma unroll
    for (int nt = 0; nt < 4; nt++) {
      int o = nt*16 + col;
      float bias = out_b[o];
      #pragma unroll
      for (int j = 0; j < 4; j++)
        outs[w*16 + gq*4 + j][o] = acc[nt][j] + bias;
    }
  }
  __syncthreads();
  int l = tid >> 2, q = tid & 3;
  int hh = wy*8 + (l>>3), ww2 = wx*8 + (l&7);
  size_t T = (size_t)b*HWp + (size_t)hh*Ww + ww2;
  float v[16];
  float s1 = 0.f, s2 = 0.f;
  #pragma unroll
  for (int i = 0; i < 16; i++) {
    int c = q*16 + i;
    float val = xT[T*64 + c] * skip1[c] + outs[l][c];
    v[i] = val; s1 += val; s2 += val*val;
  }
  s1 += __shfl_xor(s1, 1); s2 += __shfl_xor(s2, 1);
  s1 += __shfl_xor(s1, 2); s2 += __shfl_xor(s2, 2);
  float mu = s1*(1.f/64.f);
  float var = s2*(1.f/64.f) - mu*mu;
  float rstd = rsqrtf(var + 1e-5f);
  #pragma unroll
  for (int i = 0; i < 16; i++) {
    int c = q*16 + i;
    x1[T*64 + c] = v[i];
    x2[T*64 + c] = (v[i]-mu)*rstd*g2[c] + b2[c];
  }
}

// ------------------- K6: CAB conv1 3x3 64->16 + gelu (bf16 MFMA implicit GEMM) -------------------
__global__ __launch_bounds__(256) void k_conv1(
    const float* __restrict__ x2, const __hip_bfloat16* __restrict__ w1i, const float* __restrict__ bc1,
    __hip_bfloat16* __restrict__ c1){
  __shared__ __align__(16) __hip_bfloat16 xt[100][72];   // 14.4 KB
  __shared__ __align__(16) __hip_bfloat16 wt[9][16][72]; // 20.7 KB [tap][co][ci] image
  int b = blockIdx.x / WPB;
  int r = blockIdx.x % WPB;
  int by = r / NWX, bx = r % NWX;
  {
    short8v* dst = reinterpret_cast<short8v*>(&wt[0][0][0]);
    const short8v* src = reinterpret_cast<const short8v*>(w1i);
    for (int idx = threadIdx.x; idx < 1296; idx += 256) dst[idx] = src[idx];
  }
  for (int idx = threadIdx.x; idx < 1600; idx += 256) {
    int p = idx >> 4, c4 = idx & 15;
    int gy = by*8 + p/10 - 1;
    int gx = bx*8 + p%10 - 1;
    float4 v = make_float4(0.f,0.f,0.f,0.f);
    if (gy >= 0 && gy < Hh && gx >= 0 && gx < Ww)
      v = *reinterpret_cast<const float4*>(&x2[((size_t)b*HWp + (size_t)gy*Ww + gx)*64 + c4*4]);
    __hip_bfloat16 tmp[4] = {(__hip_bfloat16)v.x,(__hip_bfloat16)v.y,(__hip_bfloat16)v.z,(__hip_bfloat16)v.w};
    *reinterpret_cast<ushort4*>(&xt[p][c4*4]) = *reinterpret_cast<ushort4*>(tmp);
  }
  __syncthreads();
  int wv = threadIdx.x >> 6;
  int l  = threadIdx.x & 63;
  int col = l & 15, g = l >> 4;
  int apix = wv*16 + col;
  int apy = apix >> 3, apx = apix & 7;
  f32x4 acc = {0.f,0.f,0.f,0.f};
  #pragma unroll
  for (int tap = 0; tap < 9; tap++) {
    int ky = tap/3, kx = tap%3;
    const __hip_bfloat16* arow = &xt[(apy+ky)*10 + apx+kx][0];
    #pragma unroll
    for (int kh = 0; kh < 2; kh++) {
      short8v af = *reinterpret_cast<const short8v*>(&arow[kh*32 + g*8]);
      short8v bf = *reinterpret_cast<const short8v*>(&wt[tap][col][kh*32 + g*8]);
      acc = __builtin_amdgcn_mfma_f32_16x16x32_bf16(af, bf, acc, 0, 0, 0);
    }
  }
  float bias = bc1[col];
  #pragma unroll
  for (int j = 0; j < 4; j++) {
    int opix = wv*16 + g*4 + j;
    int oy = by*8 + (opix>>3), ox = bx*8 + (opix&7);
    float v = acc[j] + bias;
    float gv = 0.5f * v * (1.f + erff(v * 0.70710678118f));
    c1[((size_t)b*HWp + (size_t)oy*Ww + ox)*16 + col] = (__hip_bfloat16)gv;
  }
}

// ------------------- K7: CAB conv2 3x3 16->64 + partial mean (bf16 MFMA implicit GEMM) ------------
__global__ __launch_bounds__(256) void k_conv2(
    const __hip_bfloat16* __restrict__ c1, const __hip_bfloat16* __restrict__ w2i, const float* __restrict__ bc2,
    float* __restrict__ c2, float* __restrict__ sums){
  __shared__ __align__(16) __hip_bfloat16 xt[100][16];   // 3.2 KB
  __shared__ __align__(16) __hip_bfloat16 wt[5][64][40]; // 25.6 KB [pair][co][k] image
  __shared__ float red[4][64];
  int b = blockIdx.x / WPB;
  int r = blockIdx.x % WPB;
  int by = r / NWX, bx = r % NWX;
  {
    short8v* dst = reinterpret_cast<short8v*>(&wt[0][0][0]);
    const short8v* src = reinterpret_cast<const short8v*>(w2i);
    for (int idx = threadIdx.x; idx < 1600; idx += 256) dst[idx] = src[idx];
  }
  for (int idx = threadIdx.x; idx < 400; idx += 256) {
    int p = idx >> 2, c4 = idx & 3;
    int gy = by*8 + p/10 - 1;
    int gx = bx*8 + p%10 - 1;
    ushort4 v = {0,0,0,0};
    if (gy >= 0 && gy < Hh && gx >= 0 && gx < Ww)
      v = *reinterpret_cast<const ushort4*>(&c1[((size_t)b*HWp + (size_t)gy*Ww + gx)*16 + c4*4]);
    *reinterpret_cast<ushort4*>(&xt[p][c4*4]) = v;
  }
  __syncthreads();
  int wv4 = threadIdx.x >> 6;
  int l   = threadIdx.x & 63;
  int col = l & 15, g = l >> 4;
  int apix = wv4*16 + col;
  int apy = apix >> 3, apx = apix & 7;
  f32x4 acc[4] = {{0.f,0.f,0.f,0.f},{0.f,0.f,0.f,0.f},{0.f,0.f,0.f,0.f},{0.f,0.f,0.f,0.f}};
  #pragma unroll
  for (int p = 0; p < 5; p++) {
    int tap = p*2 + (g >> 1); if (tap > 8) tap = 8;
    int ky = tap/3, kx = tap%3;
    short8v af = *reinterpret_cast<const short8v*>(&xt[(apy+ky)*10 + apx+kx][(g&1)*8]);
    #pragma unroll
    for (int ct = 0; ct < 4; ct++) {
      short8v bf = *reinterpret_cast<const short8v*>(&wt[p][ct*16 + col][g*8]);
      acc[ct] = __builtin_amdgcn_mfma_f32_16x16x32_bf16(af, bf, acc[ct], 0, 0, 0);
    }
  }
  #pragma unroll
  for (int ct = 0; ct < 4; ct++) {
    int co = ct*16 + col;
    float bias = bc2[co];
    float part = 0.f;
    #pragma unroll
    for (int j = 0; j < 4; j++) {
      int opix = wv4*16 + g*4 + j;
      int oy = by*8 + (opix>>3), ox = bx*8 + (opix&7);
      float v = acc[ct][j] + bias;
      c2[((size_t)b*HWp + (size_t)oy*Ww + ox)*64 + co] = v;
      part += v;
    }
    part += __shfl_xor(part, 16);
    part += __shfl_xor(part, 32);
    if (g == 0) red[wv4][co] = part;
  }
  __syncthreads();
  if (threadIdx.x < 64) {
    float s = red[0][threadIdx.x] + red[1][threadIdx.x] + red[2][threadIdx.x] + red[3][threadIdx.x];
    atomicAdd(&sums[b*64 + threadIdx.x], s);
  }
}

// ------------------- K8: channel attention -------------------
__global__ void k_att(const float* __restrict__ sums,
                      const float* __restrict__ wd, const float* __restrict__ bd,
                      const float* __restrict__ wu, const float* __restrict__ bu,
                      float* __restrict__ att){
  int tid = threadIdx.x;            // 128 threads
  int b = tid >> 6, co = tid & 63;
  float inv = 1.f / (float)HWp;
  float hid[4];
  #pragma unroll
  for (int j = 0; j < 4; j++) {
    float acc = bd[j];
    for (int c = 0; c < 64; c++) acc += wd[j*64+c] * (sums[b*64+c] * inv);
    hid[j] = fmaxf(acc, 0.f);
  }
  float acc = bu[co];
  #pragma unroll
  for (int j = 0; j < 4; j++) acc += wu[co*4+j] * hid[j];
  att[tid] = 1.f / (1.f + __expf(-acc));
}

// ------------------- K9: final combine + NHWC -> NCHW -------------------
__global__ __launch_bounds__(256) void k_final(
    const float* __restrict__ x1, const float* __restrict__ c2,
    const float* __restrict__ skip2, const float* __restrict__ att,
    float* __restrict__ out){
  __shared__ float t[64][65];
  int b = blockIdx.x / WPB;
  int hw0 = (blockIdx.x % WPB) * 64;
  int lane = threadIdx.x & 63, grp = threadIdx.x >> 6;
  float sk = skip2[lane], at = att[b*64 + lane];
  #pragma unroll
  for (int r = 0; r < 64; r += 4) {
    int hwl = r + grp;
    size_t T = (size_t)b*HWp + hw0 + hwl;
    t[hwl][lane] = x1[T*64+lane]*sk + c2[T*64+lane]*at;
  }
  __syncthreads();
  float* ob = out + (size_t)b * Cch * HWp;
  #pragma unroll
  for (int r = 0; r < 64; r += 4) {
    int c = r + grp;
    ob[(size_t)c*HWp + hw0 + lane] = t[lane][c];
  }
}

extern "C" void kernel_launch(void* const* d_in, const int* in_sizes, int n_in,
                              void* d_out, int out_size, void* d_ws, size_t ws_size,
                              hipStream_t stream) {
  (void)in_sizes; (void)n_in; (void)out_size; (void)ws_size;
  const float* x      = (const float*)d_in[0];
  const float* ln1_g  = (const float*)d_in[1];
  const float* ln1_b  = (const float*)d_in[2];
  const float* in_w   = (const float*)d_in[3];
  const float* in_b   = (const float*)d_in[4];
  const float* conv_w = (const float*)d_in[5];
  const float* conv_b = (const float*)d_in[6];
  const float* xproj_w= (const float*)d_in[7];
  const float* dt_w   = (const float*)d_in[8];
  const float* dt_b   = (const float*)d_in[9];
  const float* A_log  = (const float*)d_in[10];
  const float* Dp     = (const float*)d_in[11];
  const float* out_w  = (const float*)d_in[12];
  const float* out_b  = (const float*)d_in[13];
  const float* skip1  = (const float*)d_in[14];
  const float* ln2_g  = (const float*)d_in[15];
  const float* ln2_b  = (const float*)d_in[16];
  const float* skip2  = (const float*)d_in[17];
  const float* cab_w1 = (const float*)d_in[18];
  const float* cab_b1 = (const float*)d_in[19];
  const float* cab_w2 = (const float*)d_in[20];
  const float* cab_b2 = (const float*)d_in[21];
  const float* ca_wd  = (const float*)d_in[22];
  const float* ca_bd  = (const float*)d_in[23];
  const float* ca_wu  = (const float*)d_in[24];
  const float* ca_bu  = (const float*)d_in[25];

  float* ws   = (float*)d_ws;
  float* xT   = ws;                        // [0, 4718592)
  __hip_bfloat16* xc = (__hip_bfloat16*)(ws + 4718592);  // bf16 9.4M elems (g in-place)
  __hip_bfloat16* z  = (__hip_bfloat16*)(ws + 14155776); // bf16 9.4M elems
  float* dbc  = ws + 23592960;             // c1 aliases later
  float* sums = ws + 26247168;             // 128
  float* att  = ws + 26247296;             // 128
  float* x1   = ws + 14155776;             // alias over z (dead after k_scan3)
  float* x2   = ws + 18874368;             // alias (z region second half)
  __hip_bfloat16* c1 = (__hip_bfloat16*)(ws + 23592960); // alias over dbc
  float* c2   = ws + 4718592;              // alias over xc/g (dead after k_out)
  // prep area (weight images)
  __hip_bfloat16* inT  = (__hip_bfloat16*)(ws + 26247424); // 18432 bf16
  __hip_bfloat16* outT = (__hip_bfloat16*)(ws + 26256640); // 8704 bf16
  __hip_bfloat16* w1i  = (__hip_bfloat16*)(ws + 26260992); // 10368 bf16
  __hip_bfloat16* w2i  = (__hip_bfloat16*)(ws + 26266176); // 12800 bf16
  float*          xpi  = ws + 26272576;                    // 4736 f

  hipMemsetAsync(sums, 0, 128*sizeof(float), stream);
  k_prep<<<215, 256, 0, stream>>>(in_w, out_w, cab_w1, cab_w2, xproj_w,
                                  inT, outT, w1i, w2i, xpi);
  k_transpose<<<NW, 256, 0, stream>>>(x, xT);
  k_stage1<<<NW, 256, 0, stream>>>(xT, ln1_g, ln1_b, inT, in_b, conv_w, conv_b, xpi,
                                   xc, z, dbc);
  k_scan3<<<NW, 128, 0, stream>>>(xc, z, dbc, dt_w, dt_b, A_log, Dp);
  k_out<<<NW, 256, 0, stream>>>(xT, xc, outT, out_b, skip1, ln2_g, ln2_b, x1, x2);
  k_conv1<<<NW, 256, 0, stream>>>(x2, w1i, cab_b1, c1);
  k_conv2<<<NW, 256, 0, stream>>>(c1, w2i, cab_b2, c2, sums);
  k_att<<<1, 128, 0, stream>>>(sums, ca_wd, ca_bd, ca_wu, ca_bu, att);
  k_final<<<NW, 256, 0, stream>>>(x1, c2, skip2, att, (float*)d_out);
}

// Round 21
// 184.822 us; speedup vs baseline: 1.1694x; 1.0998x over previous
//
#include <hip/hip_runtime.h>
#include <hip/hip_bf16.h>
#include <math.h>

// Problem constants
#define Hh 192
#define Ww 192
#define HWp (Hh*Ww)          // 36864
#define Bb 2
#define Cch 64
#define DI 128
#define NWX 24               // windows per row
#define WPB 576              // windows per batch
#define NW  1152             // total windows
#define DS 16
#define SHIFT 4

typedef __attribute__((ext_vector_type(8))) short short8v;  // 8 bf16 (4 VGPRs)
typedef __attribute__((ext_vector_type(4))) float f32x4;    // MFMA accumulator

// ------------------- K0: pre-pack weight LDS-images (once per launch) -------------------
__global__ __launch_bounds__(256) void k_prep(
    const float* __restrict__ in_w, const float* __restrict__ out_w,
    const float* __restrict__ w1, const float* __restrict__ w2, const float* __restrict__ xp,
    __hip_bfloat16* __restrict__ inT, __hip_bfloat16* __restrict__ outT,
    __hip_bfloat16* __restrict__ w1i, __hip_bfloat16* __restrict__ w2i,
    float* __restrict__ xpi){
  int i = blockIdx.x*256 + threadIdx.x;
  if (i < 18432) {
    int o = i/72, c = i%72;
    inT[i] = (__hip_bfloat16)((c < 64) ? in_w[c*256 + o] : 0.f);
    return;
  }
  i -= 18432;
  if (i < 8704) {
    int o = i/136, c = i%136;
    outT[i] = (__hip_bfloat16)((c < 128) ? out_w[c*64 + o] : 0.f);
    return;
  }
  i -= 8704;
  if (i < 10368) {
    int tap = i/1152, r = i%1152, co = r/72, ci = r%72;
    w1i[i] = (__hip_bfloat16)((ci < 64) ? w1[(co*64 + ci)*9 + tap] : 0.f);
    return;
  }
  i -= 10368;
  if (i < 12800) {
    int p = i/2560, r = i%2560, co = r/40, k = r%40;
    float v = 0.f;
    if (k < 32) { int tap = p*2 + (k>>4); int ci = k & 15; if (tap < 9) v = w2[co*144 + ci*9 + tap]; }
    w2i[i] = (__hip_bfloat16)v;
    return;
  }
  i -= 12800;
  if (i < 4736) {
    int c = i/37, j = i%37;
    xpi[i] = (j < 36) ? xp[c*36 + j] : 0.f;
  }
}

// ------------------- K1: NCHW -> NHWC transpose -------------------
__global__ __launch_bounds__(256) void k_transpose(const float* __restrict__ x, float* __restrict__ xT){
  __shared__ float t[64][65];
  int b   = blockIdx.x / WPB;
  int hw0 = (blockIdx.x % WPB) * 64;
  int lane = threadIdx.x & 63, grp = threadIdx.x >> 6;
  const float* xb = x + (size_t)b * Cch * HWp;
  #pragma unroll
  for (int r = 0; r < 64; r += 4) {
    int c = r + grp;
    t[c][lane] = xb[(size_t)c * HWp + hw0 + lane];
  }
  __syncthreads();
  float* xo = xT + ((size_t)b * HWp + hw0) * 64;
  #pragma unroll
  for (int r = 0; r < 64; r += 4) {
    int hwl = r + grp;
    xo[(size_t)hwl * 64 + lane] = t[lane][hwl];
  }
}

// ------------------- K2: shift + LN1 + in_proj(MFMA) + mask + conv1d(split) + silu + dbc ---------
__global__ __launch_bounds__(256) void k_stage1(
    const float* __restrict__ xT, const float* __restrict__ g1, const float* __restrict__ b1,
    const __hip_bfloat16* __restrict__ inT, const float* __restrict__ in_b,
    const float* __restrict__ conv_w, const float* __restrict__ conv_b,
    const float* __restrict__ xpi,
    __hip_bfloat16* __restrict__ xc, __hip_bfloat16* __restrict__ Zb, float* __restrict__ dbc){
  __shared__ __align__(16) __hip_bfloat16 xs[64][72];   // 9.2 KB
  __shared__ __align__(16) __hip_bfloat16 wt[256][72];  // 36.9 KB; reused later as wsx[128][37] f32
  __shared__ __align__(16) float XZ[64][132];           // 33.8 KB (x_in half -> xc after conv)
  float* wsx = reinterpret_cast<float*>(&wt[0][0]);
  int n = blockIdx.x;
  int b = n / WPB, wi = n % WPB;
  int wy = wi / NWX, wx = wi % NWX;
  int tid = threadIdx.x;
  {
    short8v* dst = reinterpret_cast<short8v*>(&wt[0][0]);
    const short8v* src = reinterpret_cast<const short8v*>(inT);
    for (int idx = tid; idx < 2304; idx += 256) dst[idx] = src[idx];
  }
  {
    int l = tid >> 2, q = tid & 3;
    int iy = l >> 3, ix = l & 7;
    int h = wy*8 + iy, w = wx*8 + ix;
    int hs = h + SHIFT; if (hs >= Hh) hs -= Hh;
    int ws2 = w + SHIFT; if (ws2 >= Ww) ws2 -= Ww;
    const float* src = xT + ((size_t)b*HWp + (size_t)hs*Ww + ws2) * 64 + q*16;
    float v[16];
    float s1 = 0.f, s2 = 0.f;
    #pragma unroll
    for (int k = 0; k < 4; k++) {
      float4 f = *reinterpret_cast<const float4*>(src + k*4);
      v[k*4+0]=f.x; v[k*4+1]=f.y; v[k*4+2]=f.z; v[k*4+3]=f.w;
    }
    #pragma unroll
    for (int i = 0; i < 16; i++) { s1 += v[i]; s2 += v[i]*v[i]; }
    s1 += __shfl_xor(s1, 1); s2 += __shfl_xor(s2, 1);
    s1 += __shfl_xor(s1, 2); s2 += __shfl_xor(s2, 2);
    float mu = s1 * (1.f/64.f);
    float var = s2 * (1.f/64.f) - mu*mu;
    float rstd = rsqrtf(var + 1e-5f);
    __hip_bfloat16 tmp[16];
    #pragma unroll
    for (int i = 0; i < 16; i++) {
      int c = q*16 + i;
      tmp[i] = (__hip_bfloat16)((v[i]-mu)*rstd*g1[c] + b1[c]);
    }
    *reinterpret_cast<short8v*>(&xs[l][q*16])     = *reinterpret_cast<short8v*>(&tmp[0]);
    *reinterpret_cast<short8v*>(&xs[l][q*16 + 8]) = *reinterpret_cast<short8v*>(&tmp[8]);
  }
  __syncthreads();
  {
    int w = tid >> 6, lane = tid & 63;
    int col = lane & 15, g = lane >> 4;
    short8v af[4][2];
    #pragma unroll
    for (int m = 0; m < 4; m++)
      #pragma unroll
      for (int kh = 0; kh < 2; kh++)
        af[m][kh] = *reinterpret_cast<const short8v*>(&xs[m*16 + col][kh*32 + g*8]);
    f32x4 acc[4][4];
    #pragma unroll
    for (int m = 0; m < 4; m++)
      #pragma unroll
      for (int nt = 0; nt < 4; nt++)
        acc[m][nt] = (f32x4){0.f,0.f,0.f,0.f};
    #pragma unroll
    for (int nt = 0; nt < 4; nt++) {
      int o = (w*4 + nt)*16 + col;
      #pragma unroll
      for (int kh = 0; kh < 2; kh++) {
        short8v bf = *reinterpret_cast<const short8v*>(&wt[o][kh*32 + g*8]);
        #pragma unroll
        for (int m = 0; m < 4; m++)
          acc[m][nt] = __builtin_amdgcn_mfma_f32_16x16x32_bf16(af[m][kh], bf, acc[m][nt], 0, 0, 0);
      }
    }
    #pragma unroll
    for (int nt = 0; nt < 4; nt++) {
      int colg = (w*4 + nt)*16 + col;
      float bias = in_b[colg];
      #pragma unroll
      for (int m = 0; m < 4; m++) {
        #pragma unroll
        for (int j = 0; j < 4; j++) {
          int row = m*16 + g*4 + j;
          float val = acc[m][nt][j] + bias;
          if (colg < 128) XZ[row][colg] = val;
          else Zb[((size_t)n*64 + row)*128 + (colg - 128)] = (__hip_bfloat16)val;
        }
      }
    }
  }
  __syncthreads();
  // conv epilogue: FIR split across 2 thread-halves (tokens 0-31 | 32-63), halo from XZ
  {
    int d = tid & 127, half = tid >> 7;
    int t0 = half * 32;
    float cw0 = conv_w[d], cw1 = conv_w[128+d], cw2 = conv_w[256+d], cw3 = conv_w[384+d];
    float cb = conv_b[d];
    float p1 = 0.f, p2 = 0.f, p3 = 0.f;
    if (half) {
      int hh, ww2;
      hh = wy*8 + (31>>3); ww2 = wx*8 + (31&7);
      p1 = XZ[31][d] * ((hh < Hh-SHIFT && ww2 < Ww-SHIFT) ? 1.f : 0.f);
      hh = wy*8 + (30>>3); ww2 = wx*8 + (30&7);
      p2 = XZ[30][d] * ((hh < Hh-SHIFT && ww2 < Ww-SHIFT) ? 1.f : 0.f);
      hh = wy*8 + (29>>3); ww2 = wx*8 + (29&7);
      p3 = XZ[29][d] * ((hh < Hh-SHIFT && ww2 < Ww-SHIFT) ? 1.f : 0.f);
    }
    __syncthreads();
    __hip_bfloat16* Xn = xc + (size_t)n*8192;
    #pragma unroll 4
    for (int i = 0; i < 32; i++) {
      int t = t0 + i;
      int hh = wy*8 + (t>>3), ww2 = wx*8 + (t&7);
      float m = (hh < Hh-SHIFT && ww2 < Ww-SHIFT) ? 1.f : 0.f;
      float xv = XZ[t][d] * m;
      float pre = cw3*xv + cw2*p1 + cw1*p2 + cw0*p3 + cb;
      float sv = pre / (1.f + __expf(-pre));
      Xn[t*128 + d] = (__hip_bfloat16)sv;
      XZ[t][d] = sv;
      p3 = p2; p2 = p1; p1 = xv;
    }
  }
  __syncthreads();
  {
    float4* dst = reinterpret_cast<float4*>(wsx);
    const float4* src = reinterpret_cast<const float4*>(xpi);
    for (int idx = tid; idx < 1184; idx += 256) dst[idx] = src[idx];
  }
  __syncthreads();
  // dbc GEMM: 64 tokens x 36 outs, 4 threads/token x 9 outs
  {
    int t = tid >> 2, jq = tid & 3;
    float acc[9];
    #pragma unroll
    for (int u = 0; u < 9; u++) acc[u] = 0.f;
    for (int c = 0; c < 128; c++) {
      float xv = XZ[t][c];
      #pragma unroll
      for (int u = 0; u < 9; u++) acc[u] += xv * wsx[c*37 + jq*9+u];
    }
    float* dst = dbc + ((size_t)n*64 + t)*36 + jq*9;
    #pragma unroll
    for (int u = 0; u < 9; u++) dst[u] = acc[u];
  }
}

// ------------------- K4: dt + scan + gate; db rows via wave-uniform scalar loads -----------------
__global__ __launch_bounds__(128) void k_scan3(
    __hip_bfloat16* __restrict__ xc,  // in: xc ; out: g = (y + D*xc)*silu(z)  (bf16)
    const __hip_bfloat16* __restrict__ Zb, const float* __restrict__ dbc,
    const float* __restrict__ dt_w, const float* __restrict__ dt_b,
    const float* __restrict__ A_log, const float* __restrict__ Dp){
  int n = blockIdx.x;
  int d = threadIdx.x;  // 0..127
  const float* Dn = dbc + (size_t)n*2304;
  float dtb  = dt_b[d];
  float dtw0 = dt_w[d], dtw1 = dt_w[128+d], dtw2 = dt_w[256+d], dtw3 = dt_w[384+d];
  float Dd = Dp[d];
  float a[16];
  bool pow_ok = true;
  #pragma unroll
  for (int s = 0; s < 16; s++) {
    a[s] = -__expf(A_log[d*16+s]);
    pow_ok = pow_ok && (__builtin_fabsf(a[s] + (float)(s+1)) < 1e-3f);
  }
  float h[16];
  #pragma unroll
  for (int s = 0; s < 16; s++) h[s] = 0.f;
  const __hip_bfloat16* Xn = xc + (size_t)n*8192;
  const __hip_bfloat16* Zn = Zb + (size_t)n*8192;
  __hip_bfloat16* Gn = xc + (size_t)n*8192;
  if (pow_ok) {
    #pragma unroll 2
    for (int i = 0; i < 64; i++) {
      const float* row = Dn + i*36;
      float4 dv = *reinterpret_cast<const float4*>(row);
      float4 B0 = *reinterpret_cast<const float4*>(row + 4);
      float4 B1 = *reinterpret_cast<const float4*>(row + 8);
      float4 B2 = *reinterpret_cast<const float4*>(row + 12);
      float4 B3 = *reinterpret_cast<const float4*>(row + 16);
      float4 C0 = *reinterpret_cast<const float4*>(row + 20);
      float4 C1 = *reinterpret_cast<const float4*>(row + 24);
      float4 C2 = *reinterpret_cast<const float4*>(row + 28);
      float4 C3 = *reinterpret_cast<const float4*>(row + 32);
      float pre = dtb + dv.x*dtw0 + dv.y*dtw1 + dv.z*dtw2 + dv.w*dtw3;
      float dtv = (pre > 15.f) ? pre : __logf(1.f + __expf(pre));
      float xcv = __bfloat162float(Xn[i*128 + d]);
      float zv  = __bfloat162float(Zn[i*128 + d]);
      float du  = dtv * xcv;
      float P[16];
      P[0] = __expf(-dtv);
      #pragma unroll
      for (int s = 1; s < 16; s++) {
        int aa = (s-1) >> 1, bb = (s-1) - aa;
        P[s] = P[aa] * P[bb];
      }
      h[0]  = P[0]*h[0]  + du*B0.x;  h[1]  = P[1]*h[1]  + du*B0.y;
      h[2]  = P[2]*h[2]  + du*B0.z;  h[3]  = P[3]*h[3]  + du*B0.w;
      h[4]  = P[4]*h[4]  + du*B1.x;  h[5]  = P[5]*h[5]  + du*B1.y;
      h[6]  = P[6]*h[6]  + du*B1.z;  h[7]  = P[7]*h[7]  + du*B1.w;
      h[8]  = P[8]*h[8]  + du*B2.x;  h[9]  = P[9]*h[9]  + du*B2.y;
      h[10] = P[10]*h[10]+ du*B2.z;  h[11] = P[11]*h[11]+ du*B2.w;
      h[12] = P[12]*h[12]+ du*B3.x;  h[13] = P[13]*h[13]+ du*B3.y;
      h[14] = P[14]*h[14]+ du*B3.z;  h[15] = P[15]*h[15]+ du*B3.w;
      float y0 = h[0]*C0.x + h[1]*C0.y;   y0 += h[2]*C0.z + h[3]*C0.w;
      float y1 = h[4]*C1.x + h[5]*C1.y;   y1 += h[6]*C1.z + h[7]*C1.w;
      float y2 = h[8]*C2.x + h[9]*C2.y;   y2 += h[10]*C2.z + h[11]*C2.w;
      float y3 = h[12]*C3.x + h[13]*C3.y; y3 += h[14]*C3.z + h[15]*C3.w;
      float y = (y0 + y1) + (y2 + y3);
      float yv = y + Dd*xcv;
      Gn[i*128 + d] = (__hip_bfloat16)(yv * (zv / (1.f + __expf(-zv))));
    }
  } else {
    #pragma unroll 2
    for (int i = 0; i < 64; i++) {
      const float* row = Dn + i*36;
      float4 dv = *reinterpret_cast<const float4*>(row);
      float pre = dtb + dv.x*dtw0 + dv.y*dtw1 + dv.z*dtw2 + dv.w*dtw3;
      float dtv = (pre > 15.f) ? pre : __logf(1.f + __expf(pre));
      float xcv = __bfloat162float(Xn[i*128 + d]);
      float zv  = __bfloat162float(Zn[i*128 + d]);
      float du  = dtv * xcv;
      float y = 0.f;
      #pragma unroll
      for (int s = 0; s < 16; s++) {
        float e = __expf(dtv * a[s]);
        h[s] = e*h[s] + du*row[4+s];
        y += h[s]*row[20+s];
      }
      float yv = y + Dd*xcv;
      Gn[i*128 + d] = (__hip_bfloat16)(yv * (zv / (1.f + __expf(-zv))));
    }
  }
}

// ------------------- K5: out_proj (bf16 MFMA) + window-reverse + skip1 + LN2 (bf16 outs) ---------
__global__ __launch_bounds__(256) void k_out(
    const float* __restrict__ xT, const __hip_bfloat16* __restrict__ g,
    const __hip_bfloat16* __restrict__ outT, const float* __restrict__ out_b,
    const float* __restrict__ skip1, const float* __restrict__ g2, const float* __restrict__ b2,
    __hip_bfloat16* __restrict__ x1, __hip_bfloat16* __restrict__ x2){
  __shared__ __align__(16) __hip_bfloat16 gs[64][136];  // 17.4 KB
  __shared__ __align__(16) __hip_bfloat16 wt[64][136];  // 17.4 KB
  __shared__ float outs[64][65];                        // 16.6 KB
  int n = blockIdx.x;
  int b = n / WPB, wi = n % WPB;
  int wy = wi / NWX, wx = wi % NWX;
  int tid = threadIdx.x;
  {
    const short8v* src = reinterpret_cast<const short8v*>(g + (size_t)n*8192);
    for (int idx = tid; idx < 1024; idx += 256) {
      int t = idx >> 4, seg = idx & 15;
      *reinterpret_cast<short8v*>(&gs[t][seg*8]) = src[idx];
    }
  }
  {
    short8v* dst = reinterpret_cast<short8v*>(&wt[0][0]);
    const short8v* wsrc = reinterpret_cast<const short8v*>(outT);
    for (int idx = tid; idx < 1088; idx += 256) dst[idx] = wsrc[idx];
  }
  __syncthreads();
  {
    int w = tid >> 6, lane = tid & 63;
    int col = lane & 15, gq = lane >> 4;
    f32x4 acc[4] = {{0.f,0.f,0.f,0.f},{0.f,0.f,0.f,0.f},{0.f,0.f,0.f,0.f},{0.f,0.f,0.f,0.f}};
    #pragma unroll
    for (int kh = 0; kh < 4; kh++) {
      short8v af = *reinterpret_cast<const short8v*>(&gs[w*16 + col][kh*32 + gq*8]);
      #pragma unroll
      for (int nt = 0; nt < 4; nt++) {
        short8v bf = *reinterpret_cast<const short8v*>(&wt[nt*16 + col][kh*32 + gq*8]);
        acc[nt] = __builtin_amdgcn_mfma_f32_16x16x32_bf16(af, bf, acc[nt], 0, 0, 0);
      }
    }
    #pragma unroll
    for (int nt = 0; nt < 4; nt++) {
      int o = nt*16 + col;
      float bias = out_b[o];
      #pragma unroll
      for (int j = 0; j < 4; j++)
        outs[w*16 + gq*4 + j][o] = acc[nt][j] + bias;
    }
  }
  __syncthreads();
  int l = tid >> 2, q = tid & 3;
  int hh = wy*8 + (l>>3), ww2 = wx*8 + (l&7);
  size_t T = (size_t)b*HWp + (size_t)hh*Ww + ww2;
  float v[16];
  float s1 = 0.f, s2 = 0.f;
  #pragma unroll
  for (int i = 0; i < 16; i++) {
    int c = q*16 + i;
    float val = xT[T*64 + c] * skip1[c] + outs[l][c];
    v[i] = val; s1 += val; s2 += val*val;
  }
  s1 += __shfl_xor(s1, 1); s2 += __shfl_xor(s2, 1);
  s1 += __shfl_xor(s1, 2); s2 += __shfl_xor(s2, 2);
  float mu = s1*(1.f/64.f);
  float var = s2*(1.f/64.f) - mu*mu;
  float rstd = rsqrtf(var + 1e-5f);
  __hip_bfloat16 t1[16], t2[16];
  #pragma unroll
  for (int i = 0; i < 16; i++) {
    int c = q*16 + i;
    t1[i] = (__hip_bfloat16)v[i];
    t2[i] = (__hip_bfloat16)((v[i]-mu)*rstd*g2[c] + b2[c]);
  }
  *reinterpret_cast<short8v*>(&x1[T*64 + q*16])     = *reinterpret_cast<short8v*>(&t1[0]);
  *reinterpret_cast<short8v*>(&x1[T*64 + q*16 + 8]) = *reinterpret_cast<short8v*>(&t1[8]);
  *reinterpret_cast<short8v*>(&x2[T*64 + q*16])     = *reinterpret_cast<short8v*>(&t2[0]);
  *reinterpret_cast<short8v*>(&x2[T*64 + q*16 + 8]) = *reinterpret_cast<short8v*>(&t2[8]);
}

// ------------------- K6: CAB conv1 3x3 64->16 + gelu (bf16 MFMA implicit GEMM) -------------------
__global__ __launch_bounds__(256) void k_conv1(
    const __hip_bfloat16* __restrict__ x2, const __hip_bfloat16* __restrict__ w1i, const float* __restrict__ bc1,
    __hip_bfloat16* __restrict__ c1){
  __shared__ __align__(16) __hip_bfloat16 xt[100][72];   // 14.4 KB
  __shared__ __align__(16) __hip_bfloat16 wt[9][16][72]; // 20.7 KB
  int b = blockIdx.x / WPB;
  int r = blockIdx.x % WPB;
  int by = r / NWX, bx = r % NWX;
  {
    short8v* dst = reinterpret_cast<short8v*>(&wt[0][0][0]);
    const short8v* src = reinterpret_cast<const short8v*>(w1i);
    for (int idx = threadIdx.x; idx < 1296; idx += 256) dst[idx] = src[idx];
  }
  for (int idx = threadIdx.x; idx < 800; idx += 256) {
    int p = idx >> 3, seg = idx & 7;
    int gy = by*8 + p/10 - 1;
    int gx = bx*8 + p%10 - 1;
    short8v v = {0,0,0,0,0,0,0,0};
    if (gy >= 0 && gy < Hh && gx >= 0 && gx < Ww)
      v = *reinterpret_cast<const short8v*>(&x2[((size_t)b*HWp + (size_t)gy*Ww + gx)*64 + seg*8]);
    *reinterpret_cast<short8v*>(&xt[p][seg*8]) = v;
  }
  __syncthreads();
  int wv = threadIdx.x >> 6;
  int l  = threadIdx.x & 63;
  int col = l & 15, g = l >> 4;
  int apix = wv*16 + col;
  int apy = apix >> 3, apx = apix & 7;
  f32x4 acc = {0.f,0.f,0.f,0.f};
  #pragma unroll
  for (int tap = 0; tap < 9; tap++) {
    int ky = tap/3, kx = tap%3;
    const __hip_bfloat16* arow = &xt[(apy+ky)*10 + apx+kx][0];
    #pragma unroll
    for (int kh = 0; kh < 2; kh++) {
      short8v af = *reinterpret_cast<const short8v*>(&arow[kh*32 + g*8]);
      short8v bf = *reinterpret_cast<const short8v*>(&wt[tap][col][kh*32 + g*8]);
      acc = __builtin_amdgcn_mfma_f32_16x16x32_bf16(af, bf, acc, 0, 0, 0);
    }
  }
  float bias = bc1[col];
  #pragma unroll
  for (int j = 0; j < 4; j++) {
    int opix = wv*16 + g*4 + j;
    int oy = by*8 + (opix>>3), ox = bx*8 + (opix&7);
    float v = acc[j] + bias;
    float gv = 0.5f * v * (1.f + erff(v * 0.70710678118f));
    c1[((size_t)b*HWp + (size_t)oy*Ww + ox)*16 + col] = (__hip_bfloat16)gv;
  }
}

// ------------------- K7: CAB conv2 3x3 16->64 + partial mean (bf16 MFMA implicit GEMM) ------------
__global__ __launch_bounds__(256) void k_conv2(
    const __hip_bfloat16* __restrict__ c1, const __hip_bfloat16* __restrict__ w2i, const float* __restrict__ bc2,
    __hip_bfloat16* __restrict__ c2, float* __restrict__ sums){
  __shared__ __align__(16) __hip_bfloat16 xt[100][16];   // 3.2 KB
  __shared__ __align__(16) __hip_bfloat16 wt[5][64][40]; // 25.6 KB
  __shared__ float red[4][64];
  int b = blockIdx.x / WPB;
  int r = blockIdx.x % WPB;
  int by = r / NWX, bx = r % NWX;
  {
    short8v* dst = reinterpret_cast<short8v*>(&wt[0][0][0]);
    const short8v* src = reinterpret_cast<const short8v*>(w2i);
    for (int idx = threadIdx.x; idx < 1600; idx += 256) dst[idx] = src[idx];
  }
  for (int idx = threadIdx.x; idx < 400; idx += 256) {
    int p = idx >> 2, c4 = idx & 3;
    int gy = by*8 + p/10 - 1;
    int gx = bx*8 + p%10 - 1;
    ushort4 v = {0,0,0,0};
    if (gy >= 0 && gy < Hh && gx >= 0 && gx < Ww)
      v = *reinterpret_cast<const ushort4*>(&c1[((size_t)b*HWp + (size_t)gy*Ww + gx)*16 + c4*4]);
    *reinterpret_cast<ushort4*>(&xt[p][c4*4]) = v;
  }
  __syncthreads();
  int wv4 = threadIdx.x >> 6;
  int l   = threadIdx.x & 63;
  int col = l & 15, g = l >> 4;
  int apix = wv4*16 + col;
  int apy = apix >> 3, apx = apix & 7;
  f32x4 acc[4] = {{0.f,0.f,0.f,0.f},{0.f,0.f,0.f,0.f},{0.f,0.f,0.f,0.f},{0.f,0.f,0.f,0.f}};
  #pragma unroll
  for (int p = 0; p < 5; p++) {
    int tap = p*2 + (g >> 1); if (tap > 8) tap = 8;
    int ky = tap/3, kx = tap%3;
    short8v af = *reinterpret_cast<const short8v*>(&xt[(apy+ky)*10 + apx+kx][(g&1)*8]);
    #pragma unroll
    for (int ct = 0; ct < 4; ct++) {
      short8v bf = *reinterpret_cast<const short8v*>(&wt[p][ct*16 + col][g*8]);
      acc[ct] = __builtin_amdgcn_mfma_f32_16x16x32_bf16(af, bf, acc[ct], 0, 0, 0);
    }
  }
  #pragma unroll
  for (int ct = 0; ct < 4; ct++) {
    int co = ct*16 + col;
    float bias = bc2[co];
    float part = 0.f;
    #pragma unroll
    for (int j = 0; j < 4; j++) {
      int opix = wv4*16 + g*4 + j;
      int oy = by*8 + (opix>>3), ox = bx*8 + (opix&7);
      float v = acc[ct][j] + bias;
      c2[((size_t)b*HWp + (size_t)oy*Ww + ox)*64 + co] = (__hip_bfloat16)v;
      part += v;
    }
    part += __shfl_xor(part, 16);
    part += __shfl_xor(part, 32);
    if (g == 0) red[wv4][co] = part;
  }
  __syncthreads();
  if (threadIdx.x < 64) {
    float s = red[0][threadIdx.x] + red[1][threadIdx.x] + red[2][threadIdx.x] + red[3][threadIdx.x];
    atomicAdd(&sums[b*64 + threadIdx.x], s);
  }
}

// ------------------- K8: channel attention -------------------
__global__ void k_att(const float* __restrict__ sums,
                      const float* __restrict__ wd, const float* __restrict__ bd,
                      const float* __restrict__ wu, const float* __restrict__ bu,
                      float* __restrict__ att){
  int tid = threadIdx.x;            // 128 threads
  int b = tid >> 6, co = tid & 63;
  float inv = 1.f / (float)HWp;
  float hid[4];
  #pragma unroll
  for (int j = 0; j < 4; j++) {
    float acc = bd[j];
    for (int c = 0; c < 64; c++) acc += wd[j*64+c] * (sums[b*64+c] * inv);
    hid[j] = fmaxf(acc, 0.f);
  }
  float acc = bu[co];
  #pragma unroll
  for (int j = 0; j < 4; j++) acc += wu[co*4+j] * hid[j];
  att[tid] = 1.f / (1.f + __expf(-acc));
}

// ------------------- K9: final combine + NHWC -> NCHW -------------------
__global__ __launch_bounds__(256) void k_final(
    const __hip_bfloat16* __restrict__ x1, const __hip_bfloat16* __restrict__ c2,
    const float* __restrict__ skip2, const float* __restrict__ att,
    float* __restrict__ out){
  __shared__ float t[64][65];
  int b = blockIdx.x / WPB;
  int hw0 = (blockIdx.x % WPB) * 64;
  int lane = threadIdx.x & 63, grp = threadIdx.x >> 6;
  float sk = skip2[lane], at = att[b*64 + lane];
  #pragma unroll
  for (int r = 0; r < 64; r += 4) {
    int hwl = r + grp;
    size_t T = (size_t)b*HWp + hw0 + hwl;
    float xv = __bfloat162float(x1[T*64+lane]);
    float cv = __bfloat162float(c2[T*64+lane]);
    t[hwl][lane] = xv*sk + cv*at;
  }
  __syncthreads();
  float* ob = out + (size_t)b * Cch * HWp;
  #pragma unroll
  for (int r = 0; r < 64; r += 4) {
    int c = r + grp;
    ob[(size_t)c*HWp + hw0 + lane] = t[lane][c];
  }
}

extern "C" void kernel_launch(void* const* d_in, const int* in_sizes, int n_in,
                              void* d_out, int out_size, void* d_ws, size_t ws_size,
                              hipStream_t stream) {
  (void)in_sizes; (void)n_in; (void)out_size; (void)ws_size;
  const float* x      = (const float*)d_in[0];
  const float* ln1_g  = (const float*)d_in[1];
  const float* ln1_b  = (const float*)d_in[2];
  const float* in_w   = (const float*)d_in[3];
  const float* in_b   = (const float*)d_in[4];
  const float* conv_w = (const float*)d_in[5];
  const float* conv_b = (const float*)d_in[6];
  const float* xproj_w= (const float*)d_in[7];
  const float* dt_w   = (const float*)d_in[8];
  const float* dt_b   = (const float*)d_in[9];
  const float* A_log  = (const float*)d_in[10];
  const float* Dp     = (const float*)d_in[11];
  const float* out_w  = (const float*)d_in[12];
  const float* out_b  = (const float*)d_in[13];
  const float* skip1  = (const float*)d_in[14];
  const float* ln2_g  = (const float*)d_in[15];
  const float* ln2_b  = (const float*)d_in[16];
  const float* skip2  = (const float*)d_in[17];
  const float* cab_w1 = (const float*)d_in[18];
  const float* cab_b1 = (const float*)d_in[19];
  const float* cab_w2 = (const float*)d_in[20];
  const float* cab_b2 = (const float*)d_in[21];
  const float* ca_wd  = (const float*)d_in[22];
  const float* ca_bd  = (const float*)d_in[23];
  const float* ca_wu  = (const float*)d_in[24];
  const float* ca_bu  = (const float*)d_in[25];

  float* ws   = (float*)d_ws;
  float* xT   = ws;                        // [0, 4718592)
  __hip_bfloat16* xc = (__hip_bfloat16*)(ws + 4718592);  // bf16 (g in-place)
  __hip_bfloat16* z  = (__hip_bfloat16*)(ws + 14155776); // bf16
  float* dbc  = ws + 23592960;
  float* sums = ws + 26247168;             // 128
  float* att  = ws + 26247296;             // 128
  __hip_bfloat16* x1 = (__hip_bfloat16*)(ws + 14155776); // alias over z (dead after scan)
  __hip_bfloat16* x2 = (__hip_bfloat16*)(ws + 18874368); // alias
  __hip_bfloat16* c1 = (__hip_bfloat16*)(ws + 23592960); // alias over dbc
  __hip_bfloat16* c2 = (__hip_bfloat16*)(ws + 4718592);  // alias over xc/g (dead after k_out)
  // prep area (weight images)
  __hip_bfloat16* inT  = (__hip_bfloat16*)(ws + 26247424);
  __hip_bfloat16* outT = (__hip_bfloat16*)(ws + 26256640);
  __hip_bfloat16* w1i  = (__hip_bfloat16*)(ws + 26260992);
  __hip_bfloat16* w2i  = (__hip_bfloat16*)(ws + 26266176);
  float*          xpi  = ws + 26272576;

  hipMemsetAsync(sums, 0, 128*sizeof(float), stream);
  k_prep<<<215, 256, 0, stream>>>(in_w, out_w, cab_w1, cab_w2, xproj_w,
                                  inT, outT, w1i, w2i, xpi);
  k_transpose<<<NW, 256, 0, stream>>>(x, xT);
  k_stage1<<<NW, 256, 0, stream>>>(xT, ln1_g, ln1_b, inT, in_b, conv_w, conv_b, xpi,
                                   xc, z, dbc);
  k_scan3<<<NW, 128, 0, stream>>>(xc, z, dbc, dt_w, dt_b, A_log, Dp);
  k_out<<<NW, 256, 0, stream>>>(xT, xc, outT, out_b, skip1, ln2_g, ln2_b, x1, x2);
  k_conv1<<<NW, 256, 0, stream>>>(x2, w1i, cab_b1, c1);
  k_conv2<<<NW, 256, 0, stream>>>(c1, w2i, cab_b2, c2, sums);
  k_att<<<1, 128, 0, stream>>>(sums, ca_wd, ca_bd, ca_wu, ca_bu, att);
  k_final<<<NW, 256, 0, stream>>>(x1, c2, skip2, att, (float*)d_out);
}

// Round 22
// 175.390 us; speedup vs baseline: 1.2322x; 1.0538x over previous
//
#include <hip/hip_runtime.h>
#include <hip/hip_bf16.h>
#include <math.h>

// Problem constants
#define Hh 192
#define Ww 192
#define HWp (Hh*Ww)          // 36864
#define Bb 2
#define Cch 64
#define DI 128
#define NWX 24               // windows per row
#define WPB 576              // windows per batch
#define NW  1152             // total windows
#define DS 16
#define SHIFT 4

typedef __attribute__((ext_vector_type(8))) short short8v;  // 8 bf16 (4 VGPRs)
typedef __attribute__((ext_vector_type(4))) float f32x4;    // MFMA accumulator

// ------------------- K0: pre-pack weight LDS-images + zero sums (once per launch) ----------------
__global__ __launch_bounds__(256) void k_prep(
    const float* __restrict__ in_w, const float* __restrict__ out_w,
    const float* __restrict__ w1, const float* __restrict__ w2, const float* __restrict__ xp,
    __hip_bfloat16* __restrict__ inT, __hip_bfloat16* __restrict__ outT,
    __hip_bfloat16* __restrict__ w1i, __hip_bfloat16* __restrict__ w2i,
    float* __restrict__ xpi, float* __restrict__ sums){
  int i = blockIdx.x*256 + threadIdx.x;
  if (i < 18432) {
    int o = i/72, c = i%72;
    inT[i] = (__hip_bfloat16)((c < 64) ? in_w[c*256 + o] : 0.f);
    return;
  }
  i -= 18432;
  if (i < 8704) {
    int o = i/136, c = i%136;
    outT[i] = (__hip_bfloat16)((c < 128) ? out_w[c*64 + o] : 0.f);
    return;
  }
  i -= 8704;
  if (i < 10368) {
    int tap = i/1152, r = i%1152, co = r/72, ci = r%72;
    w1i[i] = (__hip_bfloat16)((ci < 64) ? w1[(co*64 + ci)*9 + tap] : 0.f);
    return;
  }
  i -= 10368;
  if (i < 12800) {
    int p = i/2560, r = i%2560, co = r/40, k = r%40;
    float v = 0.f;
    if (k < 32) { int tap = p*2 + (k>>4); int ci = k & 15; if (tap < 9) v = w2[co*144 + ci*9 + tap]; }
    w2i[i] = (__hip_bfloat16)v;
    return;
  }
  i -= 12800;
  if (i < 4736) {
    int c = i/37, j = i%37;
    xpi[i] = (j < 36) ? xp[c*36 + j] : 0.f;
    return;
  }
  i -= 4736;
  if (i < 128) sums[i] = 0.f;
}

// ------------------- K1: NCHW -> NHWC transpose (bf16 out) -------------------
__global__ __launch_bounds__(256) void k_transpose(const float* __restrict__ x, __hip_bfloat16* __restrict__ xT){
  __shared__ float t[64][65];
  int b   = blockIdx.x / WPB;
  int hw0 = (blockIdx.x % WPB) * 64;
  int lane = threadIdx.x & 63, grp = threadIdx.x >> 6;
  const float* xb = x + (size_t)b * Cch * HWp;
  #pragma unroll
  for (int r = 0; r < 64; r += 4) {
    int c = r + grp;
    t[c][lane] = xb[(size_t)c * HWp + hw0 + lane];
  }
  __syncthreads();
  __hip_bfloat16* xo = xT + ((size_t)b * HWp + hw0) * 64;
  #pragma unroll
  for (int r = 0; r < 64; r += 4) {
    int hwl = r + grp;
    xo[(size_t)hwl * 64 + lane] = (__hip_bfloat16)t[lane][hwl];
  }
}

// ------------------- K2: shift + LN1 + in_proj(MFMA) + mask + conv1d(split) + silu + dbc ---------
__global__ __launch_bounds__(256) void k_stage1(
    const __hip_bfloat16* __restrict__ xT, const float* __restrict__ g1, const float* __restrict__ b1,
    const __hip_bfloat16* __restrict__ inT, const float* __restrict__ in_b,
    const float* __restrict__ conv_w, const float* __restrict__ conv_b,
    const float* __restrict__ xpi,
    __hip_bfloat16* __restrict__ xc, __hip_bfloat16* __restrict__ Zb, float* __restrict__ dbc){
  __shared__ __align__(16) __hip_bfloat16 xs[64][72];   // 9.2 KB
  __shared__ __align__(16) __hip_bfloat16 wt[256][72];  // 36.9 KB; reused later as wsx[128][37] f32
  __shared__ __align__(16) float XZ[64][132];           // 33.8 KB (x_in half -> xc after conv)
  float* wsx = reinterpret_cast<float*>(&wt[0][0]);
  int n = blockIdx.x;
  int b = n / WPB, wi = n % WPB;
  int wy = wi / NWX, wx = wi % NWX;
  int tid = threadIdx.x;
  {
    short8v* dst = reinterpret_cast<short8v*>(&wt[0][0]);
    const short8v* src = reinterpret_cast<const short8v*>(inT);
    for (int idx = tid; idx < 2304; idx += 256) dst[idx] = src[idx];
  }
  {
    int l = tid >> 2, q = tid & 3;
    int iy = l >> 3, ix = l & 7;
    int h = wy*8 + iy, w = wx*8 + ix;
    int hs = h + SHIFT; if (hs >= Hh) hs -= Hh;
    int ws2 = w + SHIFT; if (ws2 >= Ww) ws2 -= Ww;
    const __hip_bfloat16* src = xT + ((size_t)b*HWp + (size_t)hs*Ww + ws2) * 64 + q*16;
    __hip_bfloat16 tv[16];
    *reinterpret_cast<short8v*>(&tv[0]) = *reinterpret_cast<const short8v*>(src);
    *reinterpret_cast<short8v*>(&tv[8]) = *reinterpret_cast<const short8v*>(src + 8);
    float v[16];
    float s1 = 0.f, s2 = 0.f;
    #pragma unroll
    for (int i = 0; i < 16; i++) { v[i] = __bfloat162float(tv[i]); s1 += v[i]; s2 += v[i]*v[i]; }
    s1 += __shfl_xor(s1, 1); s2 += __shfl_xor(s2, 1);
    s1 += __shfl_xor(s1, 2); s2 += __shfl_xor(s2, 2);
    float mu = s1 * (1.f/64.f);
    float var = s2 * (1.f/64.f) - mu*mu;
    float rstd = rsqrtf(var + 1e-5f);
    __hip_bfloat16 tmp[16];
    #pragma unroll
    for (int i = 0; i < 16; i++) {
      int c = q*16 + i;
      tmp[i] = (__hip_bfloat16)((v[i]-mu)*rstd*g1[c] + b1[c]);
    }
    *reinterpret_cast<short8v*>(&xs[l][q*16])     = *reinterpret_cast<short8v*>(&tmp[0]);
    *reinterpret_cast<short8v*>(&xs[l][q*16 + 8]) = *reinterpret_cast<short8v*>(&tmp[8]);
  }
  __syncthreads();
  {
    int w = tid >> 6, lane = tid & 63;
    int col = lane & 15, g = lane >> 4;
    short8v af[4][2];
    #pragma unroll
    for (int m = 0; m < 4; m++)
      #pragma unroll
      for (int kh = 0; kh < 2; kh++)
        af[m][kh] = *reinterpret_cast<const short8v*>(&xs[m*16 + col][kh*32 + g*8]);
    f32x4 acc[4][4];
    #pragma unroll
    for (int m = 0; m < 4; m++)
      #pragma unroll
      for (int nt = 0; nt < 4; nt++)
        acc[m][nt] = (f32x4){0.f,0.f,0.f,0.f};
    #pragma unroll
    for (int nt = 0; nt < 4; nt++) {
      int o = (w*4 + nt)*16 + col;
      #pragma unroll
      for (int kh = 0; kh < 2; kh++) {
        short8v bf = *reinterpret_cast<const short8v*>(&wt[o][kh*32 + g*8]);
        #pragma unroll
        for (int m = 0; m < 4; m++)
          acc[m][nt] = __builtin_amdgcn_mfma_f32_16x16x32_bf16(af[m][kh], bf, acc[m][nt], 0, 0, 0);
      }
    }
    #pragma unroll
    for (int nt = 0; nt < 4; nt++) {
      int colg = (w*4 + nt)*16 + col;
      float bias = in_b[colg];
      #pragma unroll
      for (int m = 0; m < 4; m++) {
        #pragma unroll
        for (int j = 0; j < 4; j++) {
          int row = m*16 + g*4 + j;
          float val = acc[m][nt][j] + bias;
          if (colg < 128) XZ[row][colg] = val;
          else Zb[((size_t)n*64 + row)*128 + (colg - 128)] = (__hip_bfloat16)val;
        }
      }
    }
  }
  __syncthreads();
  // conv epilogue: FIR split across 2 thread-halves (tokens 0-31 | 32-63), halo from XZ
  {
    int d = tid & 127, half = tid >> 7;
    int t0 = half * 32;
    float cw0 = conv_w[d], cw1 = conv_w[128+d], cw2 = conv_w[256+d], cw3 = conv_w[384+d];
    float cb = conv_b[d];
    float p1 = 0.f, p2 = 0.f, p3 = 0.f;
    if (half) {
      int hh, ww2;
      hh = wy*8 + (31>>3); ww2 = wx*8 + (31&7);
      p1 = XZ[31][d] * ((hh < Hh-SHIFT && ww2 < Ww-SHIFT) ? 1.f : 0.f);
      hh = wy*8 + (30>>3); ww2 = wx*8 + (30&7);
      p2 = XZ[30][d] * ((hh < Hh-SHIFT && ww2 < Ww-SHIFT) ? 1.f : 0.f);
      hh = wy*8 + (29>>3); ww2 = wx*8 + (29&7);
      p3 = XZ[29][d] * ((hh < Hh-SHIFT && ww2 < Ww-SHIFT) ? 1.f : 0.f);
    }
    __syncthreads();
    __hip_bfloat16* Xn = xc + (size_t)n*8192;
    #pragma unroll 4
    for (int i = 0; i < 32; i++) {
      int t = t0 + i;
      int hh = wy*8 + (t>>3), ww2 = wx*8 + (t&7);
      float m = (hh < Hh-SHIFT && ww2 < Ww-SHIFT) ? 1.f : 0.f;
      float xv = XZ[t][d] * m;
      float pre = cw3*xv + cw2*p1 + cw1*p2 + cw0*p3 + cb;
      float sv = pre / (1.f + __expf(-pre));
      Xn[t*128 + d] = (__hip_bfloat16)sv;
      XZ[t][d] = sv;
      p3 = p2; p2 = p1; p1 = xv;
    }
  }
  __syncthreads();
  {
    float4* dst = reinterpret_cast<float4*>(wsx);
    const float4* src = reinterpret_cast<const float4*>(xpi);
    for (int idx = tid; idx < 1184; idx += 256) dst[idx] = src[idx];
  }
  __syncthreads();
  // dbc GEMM: 64 tokens x 36 outs, 4 threads/token x 9 outs
  {
    int t = tid >> 2, jq = tid & 3;
    float acc[9];
    #pragma unroll
    for (int u = 0; u < 9; u++) acc[u] = 0.f;
    for (int c = 0; c < 128; c++) {
      float xv = XZ[t][c];
      #pragma unroll
      for (int u = 0; u < 9; u++) acc[u] += xv * wsx[c*37 + jq*9+u];
    }
    float* dst = dbc + ((size_t)n*64 + t)*36 + jq*9;
    #pragma unroll
    for (int u = 0; u < 9; u++) dst[u] = acc[u];
  }
}

// ------------------- K4: dt + scan + gate; db rows via wave-uniform scalar loads -----------------
__global__ __launch_bounds__(128) void k_scan3(
    __hip_bfloat16* __restrict__ xc,  // in: xc ; out: g = (y + D*xc)*silu(z)  (bf16)
    const __hip_bfloat16* __restrict__ Zb, const float* __restrict__ dbc,
    const float* __restrict__ dt_w, const float* __restrict__ dt_b,
    const float* __restrict__ A_log, const float* __restrict__ Dp){
  int n = blockIdx.x;
  int d = threadIdx.x;  // 0..127
  const float* Dn = dbc + (size_t)n*2304;
  float dtb  = dt_b[d];
  float dtw0 = dt_w[d], dtw1 = dt_w[128+d], dtw2 = dt_w[256+d], dtw3 = dt_w[384+d];
  float Dd = Dp[d];
  float a[16];
  bool pow_ok = true;
  #pragma unroll
  for (int s = 0; s < 16; s++) {
    a[s] = -__expf(A_log[d*16+s]);
    pow_ok = pow_ok && (__builtin_fabsf(a[s] + (float)(s+1)) < 1e-3f);
  }
  float h[16];
  #pragma unroll
  for (int s = 0; s < 16; s++) h[s] = 0.f;
  const __hip_bfloat16* Xn = xc + (size_t)n*8192;
  const __hip_bfloat16* Zn = Zb + (size_t)n*8192;
  __hip_bfloat16* Gn = xc + (size_t)n*8192;
  if (pow_ok) {
    #pragma unroll 2
    for (int i = 0; i < 64; i++) {
      const float* row = Dn + i*36;
      float4 dv = *reinterpret_cast<const float4*>(row);
      float4 B0 = *reinterpret_cast<const float4*>(row + 4);
      float4 B1 = *reinterpret_cast<const float4*>(row + 8);
      float4 B2 = *reinterpret_cast<const float4*>(row + 12);
      float4 B3 = *reinterpret_cast<const float4*>(row + 16);
      float4 C0 = *reinterpret_cast<const float4*>(row + 20);
      float4 C1 = *reinterpret_cast<const float4*>(row + 24);
      float4 C2 = *reinterpret_cast<const float4*>(row + 28);
      float4 C3 = *reinterpret_cast<const float4*>(row + 32);
      float pre = dtb + dv.x*dtw0 + dv.y*dtw1 + dv.z*dtw2 + dv.w*dtw3;
      float dtv = (pre > 15.f) ? pre : __logf(1.f + __expf(pre));
      float xcv = __bfloat162float(Xn[i*128 + d]);
      float zv  = __bfloat162float(Zn[i*128 + d]);
      float du  = dtv * xcv;
      float P[16];
      P[0] = __expf(-dtv);
      #pragma unroll
      for (int s = 1; s < 16; s++) {
        int aa = (s-1) >> 1, bb = (s-1) - aa;
        P[s] = P[aa] * P[bb];
      }
      h[0]  = P[0]*h[0]  + du*B0.x;  h[1]  = P[1]*h[1]  + du*B0.y;
      h[2]  = P[2]*h[2]  + du*B0.z;  h[3]  = P[3]*h[3]  + du*B0.w;
      h[4]  = P[4]*h[4]  + du*B1.x;  h[5]  = P[5]*h[5]  + du*B1.y;
      h[6]  = P[6]*h[6]  + du*B1.z;  h[7]  = P[7]*h[7]  + du*B1.w;
      h[8]  = P[8]*h[8]  + du*B2.x;  h[9]  = P[9]*h[9]  + du*B2.y;
      h[10] = P[10]*h[10]+ du*B2.z;  h[11] = P[11]*h[11]+ du*B2.w;
      h[12] = P[12]*h[12]+ du*B3.x;  h[13] = P[13]*h[13]+ du*B3.y;
      h[14] = P[14]*h[14]+ du*B3.z;  h[15] = P[15]*h[15]+ du*B3.w;
      float y0 = h[0]*C0.x + h[1]*C0.y;   y0 += h[2]*C0.z + h[3]*C0.w;
      float y1 = h[4]*C1.x + h[5]*C1.y;   y1 += h[6]*C1.z + h[7]*C1.w;
      float y2 = h[8]*C2.x + h[9]*C2.y;   y2 += h[10]*C2.z + h[11]*C2.w;
      float y3 = h[12]*C3.x + h[13]*C3.y; y3 += h[14]*C3.z + h[15]*C3.w;
      float y = (y0 + y1) + (y2 + y3);
      float yv = y + Dd*xcv;
      Gn[i*128 + d] = (__hip_bfloat16)(yv * (zv / (1.f + __expf(-zv))));
    }
  } else {
    #pragma unroll 2
    for (int i = 0; i < 64; i++) {
      const float* row = Dn + i*36;
      float4 dv = *reinterpret_cast<const float4*>(row);
      float pre = dtb + dv.x*dtw0 + dv.y*dtw1 + dv.z*dtw2 + dv.w*dtw3;
      float dtv = (pre > 15.f) ? pre : __logf(1.f + __expf(pre));
      float xcv = __bfloat162float(Xn[i*128 + d]);
      float zv  = __bfloat162float(Zn[i*128 + d]);
      float du  = dtv * xcv;
      float y = 0.f;
      #pragma unroll
      for (int s = 0; s < 16; s++) {
        float e = __expf(dtv * a[s]);
        h[s] = e*h[s] + du*row[4+s];
        y += h[s]*row[20+s];
      }
      float yv = y + Dd*xcv;
      Gn[i*128 + d] = (__hip_bfloat16)(yv * (zv / (1.f + __expf(-zv))));
    }
  }
}

// ------------------- K5: out_proj (bf16 MFMA) + window-reverse + skip1 + LN2 (bf16 outs) ---------
__global__ __launch_bounds__(256) void k_out(
    const __hip_bfloat16* __restrict__ xT, const __hip_bfloat16* __restrict__ g,
    const __hip_bfloat16* __restrict__ outT, const float* __restrict__ out_b,
    const float* __restrict__ skip1, const float* __restrict__ g2, const float* __restrict__ b2,
    __hip_bfloat16* __restrict__ x1, __hip_bfloat16* __restrict__ x2){
  __shared__ __align__(16) __hip_bfloat16 gs[64][136];  // 17.4 KB
  __shared__ __align__(16) __hip_bfloat16 wt[64][136];  // 17.4 KB
  __shared__ float outs[64][65];                        // 16.6 KB
  int n = blockIdx.x;
  int b = n / WPB, wi = n % WPB;
  int wy = wi / NWX, wx = wi % NWX;
  int tid = threadIdx.x;
  {
    const short8v* src = reinterpret_cast<const short8v*>(g + (size_t)n*8192);
    for (int idx = tid; idx < 1024; idx += 256) {
      int t = idx >> 4, seg = idx & 15;
      *reinterpret_cast<short8v*>(&gs[t][seg*8]) = src[idx];
    }
  }
  {
    short8v* dst = reinterpret_cast<short8v*>(&wt[0][0]);
    const short8v* wsrc = reinterpret_cast<const short8v*>(outT);
    for (int idx = tid; idx < 1088; idx += 256) dst[idx] = wsrc[idx];
  }
  __syncthreads();
  {
    int w = tid >> 6, lane = tid & 63;
    int col = lane & 15, gq = lane >> 4;
    f32x4 acc[4] = {{0.f,0.f,0.f,0.f},{0.f,0.f,0.f,0.f},{0.f,0.f,0.f,0.f},{0.f,0.f,0.f,0.f}};
    #pragma unroll
    for (int kh = 0; kh < 4; kh++) {
      short8v af = *reinterpret_cast<const short8v*>(&gs[w*16 + col][kh*32 + gq*8]);
      #pragma unroll
      for (int nt = 0; nt < 4; nt++) {
        short8v bf = *reinterpret_cast<const short8v*>(&wt[nt*16 + col][kh*32 + gq*8]);
        acc[nt] = __builtin_amdgcn_mfma_f32_16x16x32_bf16(af, bf, acc[nt], 0, 0, 0);
      }
    }
    #pragma unroll
    for (int nt = 0; nt < 4; nt++) {
      int o = nt*16 + col;
      float bias = out_b[o];
      #pragma unroll
      for (int j = 0; j < 4; j++)
        outs[w*16 + gq*4 + j][o] = acc[nt][j] + bias;
    }
  }
  __syncthreads();
  int l = tid >> 2, q = tid & 3;
  int hh = wy*8 + (l>>3), ww2 = wx*8 + (l&7);
  size_t T = (size_t)b*HWp + (size_t)hh*Ww + ww2;
  __hip_bfloat16 sc[16];
  *reinterpret_cast<short8v*>(&sc[0]) = *reinterpret_cast<const short8v*>(&xT[T*64 + q*16]);
  *reinterpret_cast<short8v*>(&sc[8]) = *reinterpret_cast<const short8v*>(&xT[T*64 + q*16 + 8]);
  float v[16];
  float s1 = 0.f, s2 = 0.f;
  #pragma unroll
  for (int i = 0; i < 16; i++) {
    int c = q*16 + i;
    float val = __bfloat162float(sc[i]) * skip1[c] + outs[l][c];
    v[i] = val; s1 += val; s2 += val*val;
  }
  s1 += __shfl_xor(s1, 1); s2 += __shfl_xor(s2, 1);
  s1 += __shfl_xor(s1, 2); s2 += __shfl_xor(s2, 2);
  float mu = s1*(1.f/64.f);
  float var = s2*(1.f/64.f) - mu*mu;
  float rstd = rsqrtf(var + 1e-5f);
  __hip_bfloat16 t1[16], t2[16];
  #pragma unroll
  for (int i = 0; i < 16; i++) {
    int c = q*16 + i;
    t1[i] = (__hip_bfloat16)v[i];
    t2[i] = (__hip_bfloat16)((v[i]-mu)*rstd*g2[c] + b2[c]);
  }
  *reinterpret_cast<short8v*>(&x1[T*64 + q*16])     = *reinterpret_cast<short8v*>(&t1[0]);
  *reinterpret_cast<short8v*>(&x1[T*64 + q*16 + 8]) = *reinterpret_cast<short8v*>(&t1[8]);
  *reinterpret_cast<short8v*>(&x2[T*64 + q*16])     = *reinterpret_cast<short8v*>(&t2[0]);
  *reinterpret_cast<short8v*>(&x2[T*64 + q*16 + 8]) = *reinterpret_cast<short8v*>(&t2[8]);
}

// ------------------- K6: CAB conv1 3x3 64->16 + gelu (bf16 MFMA implicit GEMM) -------------------
__global__ __launch_bounds__(256) void k_conv1(
    const __hip_bfloat16* __restrict__ x2, const __hip_bfloat16* __restrict__ w1i, const float* __restrict__ bc1,
    __hip_bfloat16* __restrict__ c1){
  __shared__ __align__(16) __hip_bfloat16 xt[100][72];   // 14.4 KB
  __shared__ __align__(16) __hip_bfloat16 wt[9][16][72]; // 20.7 KB
  int b = blockIdx.x / WPB;
  int r = blockIdx.x % WPB;
  int by = r / NWX, bx = r % NWX;
  {
    short8v* dst = reinterpret_cast<short8v*>(&wt[0][0][0]);
    const short8v* src = reinterpret_cast<const short8v*>(w1i);
    for (int idx = threadIdx.x; idx < 1296; idx += 256) dst[idx] = src[idx];
  }
  for (int idx = threadIdx.x; idx < 800; idx += 256) {
    int p = idx >> 3, seg = idx & 7;
    int gy = by*8 + p/10 - 1;
    int gx = bx*8 + p%10 - 1;
    short8v v = {0,0,0,0,0,0,0,0};
    if (gy >= 0 && gy < Hh && gx >= 0 && gx < Ww)
      v = *reinterpret_cast<const short8v*>(&x2[((size_t)b*HWp + (size_t)gy*Ww + gx)*64 + seg*8]);
    *reinterpret_cast<short8v*>(&xt[p][seg*8]) = v;
  }
  __syncthreads();
  int wv = threadIdx.x >> 6;
  int l  = threadIdx.x & 63;
  int col = l & 15, g = l >> 4;
  int apix = wv*16 + col;
  int apy = apix >> 3, apx = apix & 7;
  f32x4 acc = {0.f,0.f,0.f,0.f};
  #pragma unroll
  for (int tap = 0; tap < 9; tap++) {
    int ky = tap/3, kx = tap%3;
    const __hip_bfloat16* arow = &xt[(apy+ky)*10 + apx+kx][0];
    #pragma unroll
    for (int kh = 0; kh < 2; kh++) {
      short8v af = *reinterpret_cast<const short8v*>(&arow[kh*32 + g*8]);
      short8v bf = *reinterpret_cast<const short8v*>(&wt[tap][col][kh*32 + g*8]);
      acc = __builtin_amdgcn_mfma_f32_16x16x32_bf16(af, bf, acc, 0, 0, 0);
    }
  }
  float bias = bc1[col];
  #pragma unroll
  for (int j = 0; j < 4; j++) {
    int opix = wv*16 + g*4 + j;
    int oy = by*8 + (opix>>3), ox = bx*8 + (opix&7);
    float v = acc[j] + bias;
    float gv = 0.5f * v * (1.f + erff(v * 0.70710678118f));
    c1[((size_t)b*HWp + (size_t)oy*Ww + ox)*16 + col] = (__hip_bfloat16)gv;
  }
}

// ------------------- K7: CAB conv2 3x3 16->64 + partial mean (bf16 MFMA implicit GEMM) ------------
__global__ __launch_bounds__(256) void k_conv2(
    const __hip_bfloat16* __restrict__ c1, const __hip_bfloat16* __restrict__ w2i, const float* __restrict__ bc2,
    __hip_bfloat16* __restrict__ c2, float* __restrict__ sums){
  __shared__ __align__(16) __hip_bfloat16 xt[100][16];   // 3.2 KB
  __shared__ __align__(16) __hip_bfloat16 wt[5][64][40]; // 25.6 KB
  __shared__ float red[4][64];
  int b = blockIdx.x / WPB;
  int r = blockIdx.x % WPB;
  int by = r / NWX, bx = r % NWX;
  {
    short8v* dst = reinterpret_cast<short8v*>(&wt[0][0][0]);
    const short8v* src = reinterpret_cast<const short8v*>(w2i);
    for (int idx = threadIdx.x; idx < 1600; idx += 256) dst[idx] = src[idx];
  }
  for (int idx = threadIdx.x; idx < 400; idx += 256) {
    int p = idx >> 2, c4 = idx & 3;
    int gy = by*8 + p/10 - 1;
    int gx = bx*8 + p%10 - 1;
    ushort4 v = {0,0,0,0};
    if (gy >= 0 && gy < Hh && gx >= 0 && gx < Ww)
      v = *reinterpret_cast<const ushort4*>(&c1[((size_t)b*HWp + (size_t)gy*Ww + gx)*16 + c4*4]);
    *reinterpret_cast<ushort4*>(&xt[p][c4*4]) = v;
  }
  __syncthreads();
  int wv4 = threadIdx.x >> 6;
  int l   = threadIdx.x & 63;
  int col = l & 15, g = l >> 4;
  int apix = wv4*16 + col;
  int apy = apix >> 3, apx = apix & 7;
  f32x4 acc[4] = {{0.f,0.f,0.f,0.f},{0.f,0.f,0.f,0.f},{0.f,0.f,0.f,0.f},{0.f,0.f,0.f,0.f}};
  #pragma unroll
  for (int p = 0; p < 5; p++) {
    int tap = p*2 + (g >> 1); if (tap > 8) tap = 8;
    int ky = tap/3, kx = tap%3;
    short8v af = *reinterpret_cast<const short8v*>(&xt[(apy+ky)*10 + apx+kx][(g&1)*8]);
    #pragma unroll
    for (int ct = 0; ct < 4; ct++) {
      short8v bf = *reinterpret_cast<const short8v*>(&wt[p][ct*16 + col][g*8]);
      acc[ct] = __builtin_amdgcn_mfma_f32_16x16x32_bf16(af, bf, acc[ct], 0, 0, 0);
    }
  }
  #pragma unroll
  for (int ct = 0; ct < 4; ct++) {
    int co = ct*16 + col;
    float bias = bc2[co];
    float part = 0.f;
    #pragma unroll
    for (int j = 0; j < 4; j++) {
      int opix = wv4*16 + g*4 + j;
      int oy = by*8 + (opix>>3), ox = bx*8 + (opix&7);
      float v = acc[ct][j] + bias;
      c2[((size_t)b*HWp + (size_t)oy*Ww + ox)*64 + co] = (__hip_bfloat16)v;
      part += v;
    }
    part += __shfl_xor(part, 16);
    part += __shfl_xor(part, 32);
    if (g == 0) red[wv4][co] = part;
  }
  __syncthreads();
  if (threadIdx.x < 64) {
    float s = red[0][threadIdx.x] + red[1][threadIdx.x] + red[2][threadIdx.x] + red[3][threadIdx.x];
    atomicAdd(&sums[b*64 + threadIdx.x], s);
  }
}

// ------------------- K9: channel attention (fused) + final combine + NHWC -> NCHW ----------------
__global__ __launch_bounds__(256) void k_final(
    const __hip_bfloat16* __restrict__ x1, const __hip_bfloat16* __restrict__ c2,
    const float* __restrict__ skip2, const float* __restrict__ sums,
    const float* __restrict__ wd, const float* __restrict__ bd,
    const float* __restrict__ wu, const float* __restrict__ bu,
    float* __restrict__ out){
  __shared__ float t[64][65];
  __shared__ float hid_s[4];
  __shared__ float att_s[64];
  int b = blockIdx.x / WPB;
  int hw0 = (blockIdx.x % WPB) * 64;
  int lane = threadIdx.x & 63, grp = threadIdx.x >> 6;
  // per-block channel attention (redundant, tiny, L2-hot)
  if (threadIdx.x < 4) {
    int j = threadIdx.x;
    float inv = 1.f / (float)HWp;
    float acc = bd[j];
    for (int c = 0; c < 64; c++) acc += wd[j*64+c] * (sums[b*64+c] * inv);
    hid_s[j] = fmaxf(acc, 0.f);
  }
  __syncthreads();
  if (threadIdx.x < 64) {
    int co = threadIdx.x;
    float acc = bu[co];
    #pragma unroll
    for (int j = 0; j < 4; j++) acc += wu[co*4+j] * hid_s[j];
    att_s[co] = 1.f / (1.f + __expf(-acc));
  }
  __syncthreads();
  float sk = skip2[lane], at = att_s[lane];
  #pragma unroll
  for (int r = 0; r < 64; r += 4) {
    int hwl = r + grp;
    size_t T = (size_t)b*HWp + hw0 + hwl;
    float xv = __bfloat162float(x1[T*64+lane]);
    float cv = __bfloat162float(c2[T*64+lane]);
    t[hwl][lane] = xv*sk + cv*at;
  }
  __syncthreads();
  float* ob = out + (size_t)b * Cch * HWp;
  #pragma unroll
  for (int r = 0; r < 64; r += 4) {
    int c = r + grp;
    ob[(size_t)c*HWp + hw0 + lane] = t[lane][c];
  }
}

extern "C" void kernel_launch(void* const* d_in, const int* in_sizes, int n_in,
                              void* d_out, int out_size, void* d_ws, size_t ws_size,
                              hipStream_t stream) {
  (void)in_sizes; (void)n_in; (void)out_size; (void)ws_size;
  const float* x      = (const float*)d_in[0];
  const float* ln1_g  = (const float*)d_in[1];
  const float* ln1_b  = (const float*)d_in[2];
  const float* in_w   = (const float*)d_in[3];
  const float* in_b   = (const float*)d_in[4];
  const float* conv_w = (const float*)d_in[5];
  const float* conv_b = (const float*)d_in[6];
  const float* xproj_w= (const float*)d_in[7];
  const float* dt_w   = (const float*)d_in[8];
  const float* dt_b   = (const float*)d_in[9];
  const float* A_log  = (const float*)d_in[10];
  const float* Dp     = (const float*)d_in[11];
  const float* out_w  = (const float*)d_in[12];
  const float* out_b  = (const float*)d_in[13];
  const float* skip1  = (const float*)d_in[14];
  const float* ln2_g  = (const float*)d_in[15];
  const float* ln2_b  = (const float*)d_in[16];
  const float* skip2  = (const float*)d_in[17];
  const float* cab_w1 = (const float*)d_in[18];
  const float* cab_b1 = (const float*)d_in[19];
  const float* cab_w2 = (const float*)d_in[20];
  const float* cab_b2 = (const float*)d_in[21];
  const float* ca_wd  = (const float*)d_in[22];
  const float* ca_bd  = (const float*)d_in[23];
  const float* ca_wu  = (const float*)d_in[24];
  const float* ca_bu  = (const float*)d_in[25];

  float* ws   = (float*)d_ws;
  __hip_bfloat16* xT = (__hip_bfloat16*)ws;              // bf16 4.7M elems
  __hip_bfloat16* xc = (__hip_bfloat16*)(ws + 4718592);  // bf16 (g in-place)
  __hip_bfloat16* z  = (__hip_bfloat16*)(ws + 14155776); // bf16
  float* dbc  = ws + 23592960;
  float* sums = ws + 26247168;             // 128
  __hip_bfloat16* x1 = (__hip_bfloat16*)(ws + 14155776); // alias over z (dead after scan)
  __hip_bfloat16* x2 = (__hip_bfloat16*)(ws + 18874368); // alias
  __hip_bfloat16* c1 = (__hip_bfloat16*)(ws + 23592960); // alias over dbc
  __hip_bfloat16* c2 = (__hip_bfloat16*)(ws + 4718592);  // alias over xc/g (dead after k_out)
  // prep area (weight images)
  __hip_bfloat16* inT  = (__hip_bfloat16*)(ws + 26247424);
  __hip_bfloat16* outT = (__hip_bfloat16*)(ws + 26256640);
  __hip_bfloat16* w1i  = (__hip_bfloat16*)(ws + 26260992);
  __hip_bfloat16* w2i  = (__hip_bfloat16*)(ws + 26266176);
  float*          xpi  = ws + 26272576;

  k_prep<<<216, 256, 0, stream>>>(in_w, out_w, cab_w1, cab_w2, xproj_w,
                                  inT, outT, w1i, w2i, xpi, sums);
  k_transpose<<<NW, 256, 0, stream>>>(x, xT);
  k_stage1<<<NW, 256, 0, stream>>>(xT, ln1_g, ln1_b, inT, in_b, conv_w, conv_b, xpi,
                                   xc, z, dbc);
  k_scan3<<<NW, 128, 0, stream>>>(xc, z, dbc, dt_w, dt_b, A_log, Dp);
  k_out<<<NW, 256, 0, stream>>>(xT, xc, outT, out_b, skip1, ln2_g, ln2_b, x1, x2);
  k_conv1<<<NW, 256, 0, stream>>>(x2, w1i, cab_b1, c1);
  k_conv2<<<NW, 256, 0, stream>>>(c1, w2i, cab_b2, c2, sums);
  k_final<<<NW, 256, 0, stream>>>(x1, c2, skip2, sums, ca_wd, ca_bd, ca_wu, ca_bu,
                                  (float*)d_out);
}